// Round 11
// baseline (158.051 us; speedup 1.0000x reference)
//
#include <hip/hip_runtime.h>

#define BB 512
#define TT 1024
#define GG 32
#define LL 32
#define NINF -10000000000.0f

typedef float fvec4 __attribute__((ext_vector_type(4)));   // native vector for nt stores

// DPP ctrls: quad_perm xor1=0xB1, xor2=0x4E; row_half_mirror(^7)=0x141
template<int CTRL>
__device__ __forceinline__ float dppf(float x) {
    return __builtin_bit_cast(float, __builtin_amdgcn_update_dpp(
        0, __builtin_bit_cast(int, x), CTRL, 0xF, 0xF, true));
}
// 8-lane-group butterfly reduce (^1, ^2, ^7) — replicated to all 8 lanes
__device__ __forceinline__ float gsum8(float x) {
    x += dppf<0xB1>(x); x += dppf<0x4E>(x); x += dppf<0x141>(x); return x;
}
__device__ __forceinline__ float gmax8(float x) {
    x = fmaxf(x, dppf<0xB1>(x)); x = fmaxf(x, dppf<0x4E>(x)); x = fmaxf(x, dppf<0x141>(x)); return x;
}

#define GATHER8(A0, A1, A2, A3, A4, A5, A6, A7)      \
    const float A1 = dppf<0xB1>(A0);                 \
    const float A2 = dppf<0x4E>(A0);                 \
    const float A7 = dppf<0x141>(A0);                \
    const float A3 = dppf<0x4E>(A1);                 \
    const float A6 = dppf<0xB1>(A7);                 \
    const float A5 = dppf<0x4E>(A7);                 \
    const float A4 = dppf<0x4E>(A6);

#define FMASUM(ACC, K0, K1, A0,A1,A2,A3,A4,A5,A6,A7) \
    float ACC;                                       \
    {   float accA = K0.x * A0;                      \
        accA = fmaf(K0.y, A1, accA);                 \
        accA = fmaf(K0.z, A2, accA);                 \
        accA = fmaf(K0.w, A3, accA);                 \
        float accB = K1.x * A4;                      \
        accB = fmaf(K1.y, A5, accB);                 \
        accB = fmaf(K1.z, A6, accB);                 \
        ACC = accA + accB; }

// ============ Phase A: per-segment 8x8 transfer matrices ============
// blocks [0,4096) fwd, [4096,8192) bwd; 4 tasks(waves)/block; task=(seq,seg)
// lane: group hi = matrix column (basis index), lo = state row.
__global__ __launch_bounds__(256) void segmat_kernel(
    const int* __restrict__ s, const int* __restrict__ x, const float* __restrict__ mask,
    const float* __restrict__ P, const float* __restrict__ K,
    float* __restrict__ FM, float* __restrict__ BM)
{
    __shared__ float kTab[5 * 68];   // row stride 68 floats (272B): [sv][i*8+r]
    __shared__ int   ctrlA[4][LL];
    const int tid = threadIdx.x;
    const int wv = tid >> 6, l = tid & 63;
    const int lo = l & 7, hi = l >> 3;
    const bool isF = blockIdx.x < 4096;
    const int task = (isF ? blockIdx.x : blockIdx.x - 4096) * 4 + wv;
    const int seq = task >> 5, seg = task & 31;
    const int sb = seq * TT;
    const int t0 = seg * LL;

    for (int e = tid; e < 340; e += 256) {
        const int ss = e / 68, idx = e - ss * 68;
        float v = 0.0f;
        if (idx < 64) {
            const int row = idx >> 3, r = idx & 7;
            v = isF ? K[ss*64 + row*8 + (row ^ r)]      // K[s][i][i^r]
                    : K[ss*64 + (row ^ r)*8 + row];     // K[s][i^r][i]
        }
        kTab[e] = v;
    }
    if (l < LL) {
        const int tt = t0 + l;
        ctrlA[wv][l] = s[sb+tt] | (x[sb+tt] << 3) | ((mask[sb+tt] != 0.0f) ? 16 : 0);
    }
    __syncthreads();

    const float pL0 = P[lo*2+0], pL1 = P[lo*2+1];
    const float* kbase = kTab + lo*8;
    float av = (lo == hi) ? 1.0f : 0.0f;   // identity column hi
    float c = 0.0f;

    if (isF) {
#pragma unroll 4
        for (int u = 0; u < LL; ++u) {
            const int cw = __builtin_amdgcn_readfirstlane(ctrlA[wv][u]);
            if (cw & 16) {
                const float* kp = kbase + (cw & 7) * 68;
                const float4 k0 = *(const float4*)kp;
                const float4 k1 = *(const float4*)(kp + 4);
                const float a0 = av;
                GATHER8(a0, a1, a2, a3, a4, a5, a6, a7)
                FMASUM(acc, k0, k1, a0,a1,a2,a3,a4,a5,a6,a7)
                av = acc * ((cw & 8) ? pL1 : pL0);
            }
            if ((u & 3) == 3) {
                const float ms = gmax8(av);
                av *= __builtin_amdgcn_rcpf(ms);
                c += __logf(ms);
            }
        }
        FM[task*64 + l] = __logf(av) + c;
    } else {
        // incoming carry: sxc = (s,x) at smallest masked t'' >= t1; m1 = mask[t1]
        const int t1 = t0 + LL;
        int sxc = 0;
        for (int tt = t1; tt < TT; ++tt) {
            if (mask[sb + tt] != 0.0f) { sxc = s[sb+tt] | (x[sb+tt] << 3); break; }
        }
        int m1 = (t1 < TT && mask[sb + t1] != 0.0f) ? 16 : 0;
        sxc = __builtin_amdgcn_readfirstlane(sxc);
        m1  = __builtin_amdgcn_readfirstlane(m1);
#pragma unroll 4
        for (int u = LL - 1; u >= 0; --u) {
            const int cw = __builtin_amdgcn_readfirstlane(ctrlA[wv][u]);
            if (m1) {
                const float* kp = kbase + (sxc & 7) * 68;
                const float4 k0 = *(const float4*)kp;
                const float4 k1 = *(const float4*)(kp + 4);
                const float u0 = av * ((sxc & 8) ? pL1 : pL0);
                GATHER8(u0, u1, u2, u3, u4, u5, u6, u7)
                FMASUM(acc, k0, k1, u0,u1,u2,u3,u4,u5,u6,u7)
                av = acc;
            }
            sxc = (cw & 16) ? (cw & 15) : sxc;
            m1 = cw & 16;
            if ((u & 3) == 0) {
                const float ms = gmax8(av);
                av *= __builtin_amdgcn_rcpf(ms);
                c += __logf(ms);
            }
        }
        BM[task*64 + l] = __logf(av) + c;
    }
}

// ============ Phase B: compose segment matrices (log-space LSE matvec) ============
// 1024 tasks (512 fwd seq, 512 bwd seq), 8 lanes each.
__global__ __launch_bounds__(256) void compose_kernel(
    const float* __restrict__ pi, const float* __restrict__ FM, const float* __restrict__ BM,
    float* __restrict__ SV, float* __restrict__ WV, float* __restrict__ loglik)
{
    const int tid = threadIdx.x;
    const int grp = blockIdx.x * 32 + (tid >> 3);
    const int i = tid & 7;
    if (grp < BB) {
        const int seq = grp;
        float v = __logf(pi[i]);
        for (int g = 0; g < GG; ++g) {
            SV[(seq*GG + g)*8 + i] = v;                 // incoming log-alpha state
            const float* M = FM + (size_t)(seq*GG + g) * 64;
            const float a0 = v;
            GATHER8(a0, a1, a2, a3, a4, a5, a6, a7)
            const float q0 = M[(i^0)*8 + i] + a0;
            const float q1 = M[(i^1)*8 + i] + a1;
            const float q2 = M[(i^2)*8 + i] + a2;
            const float q3 = M[(i^3)*8 + i] + a3;
            const float q4 = M[(i^4)*8 + i] + a4;
            const float q5 = M[(i^5)*8 + i] + a5;
            const float q6 = M[(i^6)*8 + i] + a6;
            const float q7 = M[(i^7)*8 + i] + a7;
            float m = fmaxf(q0, q1); m = fmaxf(m, q2); m = fmaxf(m, q3);
            m = fmaxf(m, q4); m = fmaxf(m, q5); m = fmaxf(m, q6); m = fmaxf(m, q7);
            float sum = __expf(q0-m) + __expf(q1-m) + __expf(q2-m) + __expf(q3-m)
                      + __expf(q4-m) + __expf(q5-m) + __expf(q6-m) + __expf(q7-m);
            v = m + __logf(sum);
        }
        const float gm = gmax8(v);
        const float ge = gsum8(__expf(v - gm));
        if (i == 0) loglik[seq] = gm + __logf(ge);
    } else {
        const int seq = grp - BB;
        float v = 0.0f;
        for (int g = GG - 1; g >= 0; --g) {
            WV[(seq*GG + g)*8 + i] = v;                 // incoming log-beta (raw) state
            const float* M = BM + (size_t)(seq*GG + g) * 64;
            const float a0 = v;
            GATHER8(a0, a1, a2, a3, a4, a5, a6, a7)
            const float q0 = M[(i^0)*8 + i] + a0;
            const float q1 = M[(i^1)*8 + i] + a1;
            const float q2 = M[(i^2)*8 + i] + a2;
            const float q3 = M[(i^3)*8 + i] + a3;
            const float q4 = M[(i^4)*8 + i] + a4;
            const float q5 = M[(i^5)*8 + i] + a5;
            const float q6 = M[(i^6)*8 + i] + a6;
            const float q7 = M[(i^7)*8 + i] + a7;
            float m = fmaxf(q0, q1); m = fmaxf(m, q2); m = fmaxf(m, q3);
            m = fmaxf(m, q4); m = fmaxf(m, q5); m = fmaxf(m, q6); m = fmaxf(m, q7);
            float sum = __expf(q0-m) + __expf(q1-m) + __expf(q2-m) + __expf(q3-m)
                      + __expf(q4-m) + __expf(q5-m) + __expf(q6-m) + __expf(q7-m);
            v = m + __logf(sum);
        }
    }
}

// ============ Phase C: replay segments (exact step math; beta normalized in-store) ============
// blocks [0,512) fwd, [512,1024) bwd; 4 tasks/block; task=(seqgroup, seg)
__global__ __launch_bounds__(256) void replay_kernel(
    const int* __restrict__ s, const int* __restrict__ x, const float* __restrict__ mask,
    const float* __restrict__ P, const float* __restrict__ K,
    const float* __restrict__ SV, const float* __restrict__ WV,
    const float* __restrict__ loglik,
    float* __restrict__ alpha, float* __restrict__ beta)
{
    __shared__ float kTab[5 * 68];
    __shared__ int   ctrlC[4][LL * 8];   // [slot u][g]
    const int tid = threadIdx.x;
    const int wv = tid >> 6, l = tid & 63;
    const int lo = l & 7, g = l >> 3;
    const bool isF = blockIdx.x < 512;
    const int task = (isF ? blockIdx.x : blockIdx.x - 512) * 4 + wv;
    const int sgp = task >> 5, seg = task & 31;
    const int bfirst = sgp * 8;
    const int seq = bfirst + g;
    const int sb = seq * TT;
    const int t0 = seg * LL;

    for (int e = tid; e < 340; e += 256) {
        const int ss = e / 68, idx = e - ss * 68;
        float v = 0.0f;
        if (idx < 64) {
            const int row = idx >> 3, r = idx & 7;
            v = isF ? K[ss*64 + row*8 + (row ^ r)]
                    : K[ss*64 + (row ^ r)*8 + row];
        }
        kTab[e] = v;
    }
    for (int e = l; e < LL * 8; e += 64) {
        const int slot = e >> 3, gg = e & 7;
        const int adr = (bfirst + gg) * TT + t0 + slot;
        ctrlC[wv][e] = s[adr] | (x[adr] << 3) | ((mask[adr] != 0.0f) ? 16 : 0);
    }
    __syncthreads();

    const float pL0 = P[lo*2+0], pL1 = P[lo*2+1];
    const float* kbase = kTab + lo*8;

    if (isF) {
        const float sv0 = SV[(seq*GG + seg)*8 + lo];
        const float mx = gmax8(sv0);
        float av = __expf(sv0 - mx);
        float c = mx;
        int aoff = (sb + t0) * 8 + lo;
#pragma unroll 4
        for (int u = 0; u < LL; ++u) {
            const int cw = ctrlC[wv][u*8 + g];
            const float* kp = kbase + (cw & 7) * 68;
            const float4 k0 = *(const float4*)kp;
            const float4 k1 = *(const float4*)(kp + 4);
            const float a0 = av;
            GATHER8(a0, a1, a2, a3, a4, a5, a6, a7)
            FMASUM(acc, k0, k1, a0,a1,a2,a3,a4,a5,a6,a7)
            const float nv = acc * ((cw & 8) ? pL1 : pL0);
            av = (cw & 16) ? nv : av;
            if ((u & 3) == 3) {
                const float ms = gmax8(av);
                av *= __builtin_amdgcn_rcpf(ms);
                c += __logf(ms);
            }
            __builtin_nontemporal_store(__logf(av) + c, &alpha[aoff]);
            aoff += 8;
        }
    } else {
        const float wv0 = WV[(seq*GG + seg)*8 + lo];
        const float ll = loglik[seq];
        const float mx = gmax8(wv0);
        float bv = __expf(wv0 - mx);
        float c = mx - ll;                 // fold beta normalization into the offset
        const int t1 = t0 + LL;
        int m1 = 0, sxc = 0;
        if (t1 < TT) m1 = (mask[sb + t1] != 0.0f) ? 16 : 0;
        {   // per-group bounded search for first masked index >= t1
            int tt = t1;
            int found = (t1 >= TT) ? 1 : 0;
            while (!__all(found)) {
                if (!found && tt < TT) {
                    if (mask[sb + tt] != 0.0f) { sxc = s[sb+tt] | (x[sb+tt] << 3); found = 1; }
                }
                if (tt >= TT - 1) found = 1;
                ++tt;
            }
        }
        int boff = (sb + t1 - 1) * 8 + lo;
#pragma unroll 4
        for (int u = LL - 1; u >= 0; --u) {
            const int cw = ctrlC[wv][u*8 + g];
            const float* kp = kbase + (sxc & 7) * 68;
            const float4 k0 = *(const float4*)kp;
            const float4 k1 = *(const float4*)(kp + 4);
            const float u0 = bv * ((sxc & 8) ? pL1 : pL0);
            GATHER8(u0, u1, u2, u3, u4, u5, u6, u7)
            FMASUM(acc, k0, k1, u0,u1,u2,u3,u4,u5,u6,u7)
            bv = m1 ? acc : bv;
            if ((u & 3) == 0) {
                const float ms = gmax8(bv);
                bv *= __builtin_amdgcn_rcpf(ms);
                c += __logf(ms);
            }
            __builtin_nontemporal_store(__logf(bv) + c, &beta[boff]);
            boff -= 8;
            sxc = (cw & 16) ? (cw & 15) : sxc;
            m1 = cw & 16;
        }
    }
}

// ============ gamma + xi: streaming, 4 t-rows per wave, float4 nt stores ============
// (normalizations are exact no-ops by the forward-backward invariant)
__global__ __launch_bounds__(256) void post_kernel(
    const int* __restrict__ s, const int* __restrict__ x, const float* __restrict__ mask,
    const float* __restrict__ P, const float* __restrict__ K,
    const float* __restrict__ alpha, const float* __restrict__ beta,
    float* __restrict__ gamma, float* __restrict__ xi)
{
    __shared__ float lK[320];
    __shared__ float lP0[8], lP1[8];
    const int tid = threadIdx.x;
    for (int e = tid; e < 320; e += 256) lK[e] = __logf(K[e]);
    if (tid < 8) { lP0[tid] = __logf(P[tid*2]); lP1[tid] = __logf(P[tid*2+1]); }
    __syncthreads();

    const int w = blockIdx.x * 4 + (tid >> 6);    // wave id, [0, BB*TT/4)
    const int l = tid & 63;
    const int b = w >> 8;                          // 256 waves per b
    const int t0 = (w & 255) * 4;
    const long bt0 = (long)b * TT + t0;

    // gamma: lanes 0..31 cover 4 rows x 8 states
    if (l < 32) {
        const int qg = l >> 3, z = l & 7;
        const long bt = bt0 + qg;
        const float m0 = mask[bt];
        const float a = alpha[bt*8 + z];
        const float bb = beta[bt*8 + z];
        __builtin_nontemporal_store((m0 != 0.0f) ? (a + bb) : NINF, &gamma[bt*8 + z]);
    }
    // xi: row q = l>>4, 16 lanes x float4 per row
    const int q = l >> 4, ll = l & 15;
    const long t = t0 + q;
    const long bt = bt0 + q;
    const bool wx = (t < TT - 1);
    const long tn = wx ? (bt + 1) : bt;            // safe address
    const float m1 = mask[tn];
    const int svv = s[bt];
    const int xv = x[tn];
    const int i = ll >> 1;
    const int bj = (ll & 1) * 4;
    float4 out;
    if (wx && m1 != 0.0f) {
        const float aHi = alpha[bt*8 + i];
        const float4 bN = *(const float4*)&beta[tn*8 + bj];
        const float4 kv = *(const float4*)&lK[svv*64 + ll*4];
        const float4 p0 = *(const float4*)&lP0[bj];
        const float4 p1 = *(const float4*)&lP1[bj];
        out.x = kv.x + aHi + bN.x + (xv ? p1.x : p0.x);
        out.y = kv.y + aHi + bN.y + (xv ? p1.y : p0.y);
        out.z = kv.z + aHi + bN.z + (xv ? p1.z : p0.z);
        out.w = kv.w + aHi + bN.w + (xv ? p1.w : p0.w);
    } else {
        out.x = NINF; out.y = NINF; out.z = NINF; out.w = NINF;
    }
    if (wx) __builtin_nontemporal_store(__builtin_bit_cast(fvec4, out),
                (fvec4*)&xi[((long)b*(TT-1) + t)*64 + ll*4]);
}

extern "C" void kernel_launch(void* const* d_in, const int* in_sizes, int n_in,
                              void* d_out, int out_size, void* d_ws, size_t ws_size,
                              hipStream_t stream) {
    const int*   s    = (const int*)d_in[0];
    const int*   x    = (const int*)d_in[1];
    const float* mask = (const float*)d_in[2];
    const float* pi   = (const float*)d_in[3];
    const float* P    = (const float*)d_in[4];
    const float* K    = (const float*)d_in[5];

    float* out    = (float*)d_out;
    float* gamma  = out;                                  // (B,T,Z)
    float* xi     = gamma + (size_t)BB * TT * 8;          // (B,T-1,Z,Z) = 33,521,664 floats
    float* alpha  = xi + (size_t)BB * (TT - 1) * 64;      // (B,T,Z)
    float* beta   = alpha + (size_t)BB * TT * 8;          // (B,T,Z)
    float* loglik = beta + (size_t)BB * TT * 8;           // (B,)

    // scratch inside xi tail (post overwrites xi only after replay):
    float* FMs = xi + (size_t)31000000;
    float* BMs = FMs + (size_t)BB * GG * 64;
    float* SVs = BMs + (size_t)BB * GG * 64;
    float* WVs = SVs + (size_t)BB * GG * 8;

    segmat_kernel<<<8192, 256, 0, stream>>>(s, x, mask, P, K, FMs, BMs);
    compose_kernel<<<32, 256, 0, stream>>>(pi, FMs, BMs, SVs, WVs, loglik);
    replay_kernel<<<1024, 256, 0, stream>>>(s, x, mask, P, K, SVs, WVs, loglik, alpha, beta);
    post_kernel<<<BB * TT / 16, 256, 0, stream>>>(s, x, mask, P, K, alpha, beta, gamma, xi);
}

// Round 12
// 128.791 us; speedup vs baseline: 1.2272x; 1.2272x over previous
//
#include <hip/hip_runtime.h>

#define BB 512
#define TT 1024
#define GG 32
#define LL 32
#define NINF -10000000000.0f

typedef float fvec4 __attribute__((ext_vector_type(4)));   // native vector for nt stores

// DPP ctrls: quad_perm xor1=0xB1, xor2=0x4E; row_half_mirror(^7)=0x141
template<int CTRL>
__device__ __forceinline__ float dppf(float x) {
    return __builtin_bit_cast(float, __builtin_amdgcn_update_dpp(
        0, __builtin_bit_cast(int, x), CTRL, 0xF, 0xF, true));
}
// 8-lane-group butterfly reduce (^1, ^2, ^7) — replicated to all 8 lanes
__device__ __forceinline__ float gsum8(float x) {
    x += dppf<0xB1>(x); x += dppf<0x4E>(x); x += dppf<0x141>(x); return x;
}
__device__ __forceinline__ float gmax8(float x) {
    x = fmaxf(x, dppf<0xB1>(x)); x = fmaxf(x, dppf<0x4E>(x)); x = fmaxf(x, dppf<0x141>(x)); return x;
}

#define GATHER8(A0, A1, A2, A3, A4, A5, A6, A7)      \
    const float A1 = dppf<0xB1>(A0);                 \
    const float A2 = dppf<0x4E>(A0);                 \
    const float A7 = dppf<0x141>(A0);                \
    const float A3 = dppf<0x4E>(A1);                 \
    const float A6 = dppf<0xB1>(A7);                 \
    const float A5 = dppf<0x4E>(A7);                 \
    const float A4 = dppf<0x4E>(A6);

#define FMASUM(ACC, K0, K1, A0,A1,A2,A3,A4,A5,A6,A7) \
    float ACC;                                       \
    {   float accA = K0.x * A0;                      \
        accA = fmaf(K0.y, A1, accA);                 \
        accA = fmaf(K0.z, A2, accA);                 \
        accA = fmaf(K0.w, A3, accA);                 \
        float accB = K1.x * A4;                      \
        accB = fmaf(K1.y, A5, accB);                 \
        accB = fmaf(K1.z, A6, accB);                 \
        ACC = accA + accB; }

// ============ Phase A: per-segment 8x8 transfer matrices ============
// blocks [0,4096) fwd, [4096,8192) bwd; 4 tasks(waves)/block; task=(seq,seg)
// lane: group hi = matrix column (basis index), lo = state row.
__global__ __launch_bounds__(256) void segmat_kernel(
    const int* __restrict__ s, const int* __restrict__ x, const float* __restrict__ mask,
    const float* __restrict__ P, const float* __restrict__ K,
    float* __restrict__ FM, float* __restrict__ BM)
{
    __shared__ float kTab[5 * 68];   // row stride 68 floats (272B): [sv][i*8+r]
    __shared__ int   ctrlA[4][LL];
    const int tid = threadIdx.x;
    const int wv = tid >> 6, l = tid & 63;
    const int lo = l & 7, hi = l >> 3;
    const bool isF = blockIdx.x < 4096;
    const int task = (isF ? blockIdx.x : blockIdx.x - 4096) * 4 + wv;
    const int seq = task >> 5, seg = task & 31;
    const int sb = seq * TT;
    const int t0 = seg * LL;

    for (int e = tid; e < 340; e += 256) {
        const int ss = e / 68, idx = e - ss * 68;
        float v = 0.0f;
        if (idx < 64) {
            const int row = idx >> 3, r = idx & 7;
            v = isF ? K[ss*64 + row*8 + (row ^ r)]      // K[s][i][i^r]
                    : K[ss*64 + (row ^ r)*8 + row];     // K[s][i^r][i]
        }
        kTab[e] = v;
    }
    if (l < LL) {
        const int tt = t0 + l;
        ctrlA[wv][l] = s[sb+tt] | (x[sb+tt] << 3) | ((mask[sb+tt] != 0.0f) ? 16 : 0);
    }
    __syncthreads();

    const float pL0 = P[lo*2+0], pL1 = P[lo*2+1];
    const float* kbase = kTab + lo*8;
    float av = (lo == hi) ? 1.0f : 0.0f;   // identity column hi
    float c = 0.0f;

    if (isF) {
#pragma unroll 4
        for (int u = 0; u < LL; ++u) {
            const int cw = __builtin_amdgcn_readfirstlane(ctrlA[wv][u]);
            if (cw & 16) {
                const float* kp = kbase + (cw & 7) * 68;
                const float4 k0 = *(const float4*)kp;
                const float4 k1 = *(const float4*)(kp + 4);
                const float a0 = av;
                GATHER8(a0, a1, a2, a3, a4, a5, a6, a7)
                FMASUM(acc, k0, k1, a0,a1,a2,a3,a4,a5,a6,a7)
                av = acc * ((cw & 8) ? pL1 : pL0);
            }
            if ((u & 3) == 3) {
                const float ms = gmax8(av);
                av *= __builtin_amdgcn_rcpf(ms);
                c += __logf(ms);
            }
        }
        FM[task*64 + l] = __logf(av) + c;
    } else {
        // incoming carry: sxc = (s,x) at smallest masked t'' >= t1; m1 = mask[t1]
        const int t1 = t0 + LL;
        int sxc = 0;
        for (int tt = t1; tt < TT; ++tt) {
            if (mask[sb + tt] != 0.0f) { sxc = s[sb+tt] | (x[sb+tt] << 3); break; }
        }
        int m1 = (t1 < TT && mask[sb + t1] != 0.0f) ? 16 : 0;
        sxc = __builtin_amdgcn_readfirstlane(sxc);
        m1  = __builtin_amdgcn_readfirstlane(m1);
#pragma unroll 4
        for (int u = LL - 1; u >= 0; --u) {
            const int cw = __builtin_amdgcn_readfirstlane(ctrlA[wv][u]);
            if (m1) {
                const float* kp = kbase + (sxc & 7) * 68;
                const float4 k0 = *(const float4*)kp;
                const float4 k1 = *(const float4*)(kp + 4);
                const float u0 = av * ((sxc & 8) ? pL1 : pL0);
                GATHER8(u0, u1, u2, u3, u4, u5, u6, u7)
                FMASUM(acc, k0, k1, u0,u1,u2,u3,u4,u5,u6,u7)
                av = acc;
            }
            sxc = (cw & 16) ? (cw & 15) : sxc;
            m1 = cw & 16;
            if ((u & 3) == 0) {
                const float ms = gmax8(av);
                av *= __builtin_amdgcn_rcpf(ms);
                c += __logf(ms);
            }
        }
        BM[task*64 + l] = __logf(av) + c;
    }
}

// ============ Phase B: compose segment matrices (log-space LSE matvec) ============
// 1024 tasks (512 fwd seq, 512 bwd seq), 8 lanes each.
__global__ __launch_bounds__(256) void compose_kernel(
    const float* __restrict__ pi, const float* __restrict__ FM, const float* __restrict__ BM,
    float* __restrict__ SV, float* __restrict__ WV, float* __restrict__ loglik)
{
    const int tid = threadIdx.x;
    const int grp = blockIdx.x * 32 + (tid >> 3);
    const int i = tid & 7;
    if (grp < BB) {
        const int seq = grp;
        float v = __logf(pi[i]);
        for (int g = 0; g < GG; ++g) {
            SV[(seq*GG + g)*8 + i] = v;                 // incoming log-alpha state
            const float* M = FM + (size_t)(seq*GG + g) * 64;
            const float a0 = v;
            GATHER8(a0, a1, a2, a3, a4, a5, a6, a7)
            const float q0 = M[(i^0)*8 + i] + a0;
            const float q1 = M[(i^1)*8 + i] + a1;
            const float q2 = M[(i^2)*8 + i] + a2;
            const float q3 = M[(i^3)*8 + i] + a3;
            const float q4 = M[(i^4)*8 + i] + a4;
            const float q5 = M[(i^5)*8 + i] + a5;
            const float q6 = M[(i^6)*8 + i] + a6;
            const float q7 = M[(i^7)*8 + i] + a7;
            float m = fmaxf(q0, q1); m = fmaxf(m, q2); m = fmaxf(m, q3);
            m = fmaxf(m, q4); m = fmaxf(m, q5); m = fmaxf(m, q6); m = fmaxf(m, q7);
            float sum = __expf(q0-m) + __expf(q1-m) + __expf(q2-m) + __expf(q3-m)
                      + __expf(q4-m) + __expf(q5-m) + __expf(q6-m) + __expf(q7-m);
            v = m + __logf(sum);
        }
        const float gm = gmax8(v);
        const float ge = gsum8(__expf(v - gm));
        if (i == 0) loglik[seq] = gm + __logf(ge);
    } else {
        const int seq = grp - BB;
        float v = 0.0f;
        for (int g = GG - 1; g >= 0; --g) {
            WV[(seq*GG + g)*8 + i] = v;                 // incoming log-beta (raw) state
            const float* M = BM + (size_t)(seq*GG + g) * 64;
            const float a0 = v;
            GATHER8(a0, a1, a2, a3, a4, a5, a6, a7)
            const float q0 = M[(i^0)*8 + i] + a0;
            const float q1 = M[(i^1)*8 + i] + a1;
            const float q2 = M[(i^2)*8 + i] + a2;
            const float q3 = M[(i^3)*8 + i] + a3;
            const float q4 = M[(i^4)*8 + i] + a4;
            const float q5 = M[(i^5)*8 + i] + a5;
            const float q6 = M[(i^6)*8 + i] + a6;
            const float q7 = M[(i^7)*8 + i] + a7;
            float m = fmaxf(q0, q1); m = fmaxf(m, q2); m = fmaxf(m, q3);
            m = fmaxf(m, q4); m = fmaxf(m, q5); m = fmaxf(m, q6); m = fmaxf(m, q7);
            float sum = __expf(q0-m) + __expf(q1-m) + __expf(q2-m) + __expf(q3-m)
                      + __expf(q4-m) + __expf(q5-m) + __expf(q6-m) + __expf(q7-m);
            v = m + __logf(sum);
        }
    }
}

// ============ Phase C: replay segments (exact step math; beta normalized in-store) ============
// blocks [0,512) fwd, [512,1024) bwd; 4 tasks/block; task=(seqgroup, seg)
// alpha/beta use REGULAR stores (post re-reads them through L2/L3 — nt here cost 17 µs in R11).
__global__ __launch_bounds__(256) void replay_kernel(
    const int* __restrict__ s, const int* __restrict__ x, const float* __restrict__ mask,
    const float* __restrict__ P, const float* __restrict__ K,
    const float* __restrict__ SV, const float* __restrict__ WV,
    const float* __restrict__ loglik,
    float* __restrict__ alpha, float* __restrict__ beta)
{
    __shared__ float kTab[5 * 68];
    __shared__ int   ctrlC[4][LL * 8];   // [slot u][g]
    const int tid = threadIdx.x;
    const int wv = tid >> 6, l = tid & 63;
    const int lo = l & 7, g = l >> 3;
    const bool isF = blockIdx.x < 512;
    const int task = (isF ? blockIdx.x : blockIdx.x - 512) * 4 + wv;
    const int sgp = task >> 5, seg = task & 31;
    const int bfirst = sgp * 8;
    const int seq = bfirst + g;
    const int sb = seq * TT;
    const int t0 = seg * LL;

    for (int e = tid; e < 340; e += 256) {
        const int ss = e / 68, idx = e - ss * 68;
        float v = 0.0f;
        if (idx < 64) {
            const int row = idx >> 3, r = idx & 7;
            v = isF ? K[ss*64 + row*8 + (row ^ r)]
                    : K[ss*64 + (row ^ r)*8 + row];
        }
        kTab[e] = v;
    }
    for (int e = l; e < LL * 8; e += 64) {
        const int slot = e >> 3, gg = e & 7;
        const int adr = (bfirst + gg) * TT + t0 + slot;
        ctrlC[wv][e] = s[adr] | (x[adr] << 3) | ((mask[adr] != 0.0f) ? 16 : 0);
    }
    __syncthreads();

    const float pL0 = P[lo*2+0], pL1 = P[lo*2+1];
    const float* kbase = kTab + lo*8;

    if (isF) {
        const float sv0 = SV[(seq*GG + seg)*8 + lo];
        const float mx = gmax8(sv0);
        float av = __expf(sv0 - mx);
        float c = mx;
        int aoff = (sb + t0) * 8 + lo;
#pragma unroll 4
        for (int u = 0; u < LL; ++u) {
            const int cw = ctrlC[wv][u*8 + g];
            const float* kp = kbase + (cw & 7) * 68;
            const float4 k0 = *(const float4*)kp;
            const float4 k1 = *(const float4*)(kp + 4);
            const float a0 = av;
            GATHER8(a0, a1, a2, a3, a4, a5, a6, a7)
            FMASUM(acc, k0, k1, a0,a1,a2,a3,a4,a5,a6,a7)
            const float nv = acc * ((cw & 8) ? pL1 : pL0);
            av = (cw & 16) ? nv : av;
            if ((u & 3) == 3) {
                const float ms = gmax8(av);
                av *= __builtin_amdgcn_rcpf(ms);
                c += __logf(ms);
            }
            alpha[aoff] = __logf(av) + c;
            aoff += 8;
        }
    } else {
        const float wv0 = WV[(seq*GG + seg)*8 + lo];
        const float ll = loglik[seq];
        const float mx = gmax8(wv0);
        float bv = __expf(wv0 - mx);
        float c = mx - ll;                 // fold beta normalization into the offset
        const int t1 = t0 + LL;
        int m1 = 0, sxc = 0;
        if (t1 < TT) m1 = (mask[sb + t1] != 0.0f) ? 16 : 0;
        {   // per-group bounded search for first masked index >= t1
            int tt = t1;
            int found = (t1 >= TT) ? 1 : 0;
            while (!__all(found)) {
                if (!found && tt < TT) {
                    if (mask[sb + tt] != 0.0f) { sxc = s[sb+tt] | (x[sb+tt] << 3); found = 1; }
                }
                if (tt >= TT - 1) found = 1;
                ++tt;
            }
        }
        int boff = (sb + t1 - 1) * 8 + lo;
#pragma unroll 4
        for (int u = LL - 1; u >= 0; --u) {
            const int cw = ctrlC[wv][u*8 + g];
            const float* kp = kbase + (sxc & 7) * 68;
            const float4 k0 = *(const float4*)kp;
            const float4 k1 = *(const float4*)(kp + 4);
            const float u0 = bv * ((sxc & 8) ? pL1 : pL0);
            GATHER8(u0, u1, u2, u3, u4, u5, u6, u7)
            FMASUM(acc, k0, k1, u0,u1,u2,u3,u4,u5,u6,u7)
            bv = m1 ? acc : bv;
            if ((u & 3) == 0) {
                const float ms = gmax8(bv);
                bv *= __builtin_amdgcn_rcpf(ms);
                c += __logf(ms);
            }
            beta[boff] = __logf(bv) + c;
            boff -= 8;
            sxc = (cw & 16) ? (cw & 15) : sxc;
            m1 = cw & 16;
        }
    }
}

// ============ gamma + xi: streaming, 4 t-rows per wave, nt stores (write-once data) ============
// (normalizations are exact no-ops by the forward-backward invariant)
__global__ __launch_bounds__(256) void post_kernel(
    const int* __restrict__ s, const int* __restrict__ x, const float* __restrict__ mask,
    const float* __restrict__ P, const float* __restrict__ K,
    const float* __restrict__ alpha, const float* __restrict__ beta,
    float* __restrict__ gamma, float* __restrict__ xi)
{
    __shared__ float lK[320];
    __shared__ float lP0[8], lP1[8];
    const int tid = threadIdx.x;
    for (int e = tid; e < 320; e += 256) lK[e] = __logf(K[e]);
    if (tid < 8) { lP0[tid] = __logf(P[tid*2]); lP1[tid] = __logf(P[tid*2+1]); }
    __syncthreads();

    const int w = blockIdx.x * 4 + (tid >> 6);    // wave id, [0, BB*TT/4)
    const int l = tid & 63;
    const int b = w >> 8;                          // 256 waves per b
    const int t0 = (w & 255) * 4;
    const long bt0 = (long)b * TT + t0;

    // gamma: lanes 0..31 cover 4 rows x 8 states
    if (l < 32) {
        const int qg = l >> 3, z = l & 7;
        const long bt = bt0 + qg;
        const float m0 = mask[bt];
        const float a = alpha[bt*8 + z];
        const float bb = beta[bt*8 + z];
        __builtin_nontemporal_store((m0 != 0.0f) ? (a + bb) : NINF, &gamma[bt*8 + z]);
    }
    // xi: row q = l>>4, 16 lanes x float4 per row
    const int q = l >> 4, ll = l & 15;
    const long t = t0 + q;
    const long bt = bt0 + q;
    const bool wx = (t < TT - 1);
    const long tn = wx ? (bt + 1) : bt;            // safe address
    const float m1 = mask[tn];
    const int svv = s[bt];
    const int xv = x[tn];
    const int i = ll >> 1;
    const int bj = (ll & 1) * 4;
    float4 out;
    if (wx && m1 != 0.0f) {
        const float aHi = alpha[bt*8 + i];
        const float4 bN = *(const float4*)&beta[tn*8 + bj];
        const float4 kv = *(const float4*)&lK[svv*64 + ll*4];
        const float4 p0 = *(const float4*)&lP0[bj];
        const float4 p1 = *(const float4*)&lP1[bj];
        out.x = kv.x + aHi + bN.x + (xv ? p1.x : p0.x);
        out.y = kv.y + aHi + bN.y + (xv ? p1.y : p0.y);
        out.z = kv.z + aHi + bN.z + (xv ? p1.z : p0.z);
        out.w = kv.w + aHi + bN.w + (xv ? p1.w : p0.w);
    } else {
        out.x = NINF; out.y = NINF; out.z = NINF; out.w = NINF;
    }
    if (wx) __builtin_nontemporal_store(__builtin_bit_cast(fvec4, out),
                (fvec4*)&xi[((long)b*(TT-1) + t)*64 + ll*4]);
}

extern "C" void kernel_launch(void* const* d_in, const int* in_sizes, int n_in,
                              void* d_out, int out_size, void* d_ws, size_t ws_size,
                              hipStream_t stream) {
    const int*   s    = (const int*)d_in[0];
    const int*   x    = (const int*)d_in[1];
    const float* mask = (const float*)d_in[2];
    const float* pi   = (const float*)d_in[3];
    const float* P    = (const float*)d_in[4];
    const float* K    = (const float*)d_in[5];

    float* out    = (float*)d_out;
    float* gamma  = out;                                  // (B,T,Z)
    float* xi     = gamma + (size_t)BB * TT * 8;          // (B,T-1,Z,Z) = 33,521,664 floats
    float* alpha  = xi + (size_t)BB * (TT - 1) * 64;      // (B,T,Z)
    float* beta   = alpha + (size_t)BB * TT * 8;          // (B,T,Z)
    float* loglik = beta + (size_t)BB * TT * 8;           // (B,)

    // scratch inside xi tail (post overwrites xi only after replay):
    float* FMs = xi + (size_t)31000000;
    float* BMs = FMs + (size_t)BB * GG * 64;
    float* SVs = BMs + (size_t)BB * GG * 64;
    float* WVs = SVs + (size_t)BB * GG * 8;

    segmat_kernel<<<8192, 256, 0, stream>>>(s, x, mask, P, K, FMs, BMs);
    compose_kernel<<<32, 256, 0, stream>>>(pi, FMs, BMs, SVs, WVs, loglik);
    replay_kernel<<<1024, 256, 0, stream>>>(s, x, mask, P, K, SVs, WVs, loglik, alpha, beta);
    post_kernel<<<BB * TT / 16, 256, 0, stream>>>(s, x, mask, P, K, alpha, beta, gamma, xi);
}

// Round 13
// 125.208 us; speedup vs baseline: 1.2623x; 1.0286x over previous
//
#include <hip/hip_runtime.h>

#define BB 512
#define TT 1024
#define GG 32
#define LL 32
#define NINF -10000000000.0f
#define SROW 65                 // LDS row stride (floats) for aL/bL tiles
#define NXROWS (BB * (TT - 1))  // 523776 xi rows
#define SCRATCH_ROW0 484375     // xi row where xi-tail scratch begins (31,000,000/64)

// DPP ctrls: quad_perm xor1=0xB1, xor2=0x4E; row_half_mirror(^7)=0x141
template<int CTRL>
__device__ __forceinline__ float dppf(float x) {
    return __builtin_bit_cast(float, __builtin_amdgcn_update_dpp(
        0, __builtin_bit_cast(int, x), CTRL, 0xF, 0xF, true));
}
__device__ __forceinline__ float gsum8(float x) {
    x += dppf<0xB1>(x); x += dppf<0x4E>(x); x += dppf<0x141>(x); return x;
}
__device__ __forceinline__ float gmax8(float x) {
    x = fmaxf(x, dppf<0xB1>(x)); x = fmaxf(x, dppf<0x4E>(x)); x = fmaxf(x, dppf<0x141>(x)); return x;
}

#define GATHER8(A0, A1, A2, A3, A4, A5, A6, A7)      \
    const float A1 = dppf<0xB1>(A0);                 \
    const float A2 = dppf<0x4E>(A0);                 \
    const float A7 = dppf<0x141>(A0);                \
    const float A3 = dppf<0x4E>(A1);                 \
    const float A6 = dppf<0xB1>(A7);                 \
    const float A5 = dppf<0x4E>(A7);                 \
    const float A4 = dppf<0x4E>(A6);

#define FMASUM(ACC, K0, K1, A0,A1,A2,A3,A4,A5,A6,A7) \
    float ACC;                                       \
    {   float accA = K0.x * A0;                      \
        accA = fmaf(K0.y, A1, accA);                 \
        accA = fmaf(K0.z, A2, accA);                 \
        accA = fmaf(K0.w, A3, accA);                 \
        float accB = K1.x * A4;                      \
        accB = fmaf(K1.y, A5, accB);                 \
        accB = fmaf(K1.z, A6, accB);                 \
        ACC = accA + accB; }

// ============ Phase A: per-segment 8x8 transfer matrices (R12-verified) ============
__global__ __launch_bounds__(256) void segmat_kernel(
    const int* __restrict__ s, const int* __restrict__ x, const float* __restrict__ mask,
    const float* __restrict__ P, const float* __restrict__ K,
    float* __restrict__ FM, float* __restrict__ BM)
{
    __shared__ float kTab[5 * 68];
    __shared__ int   ctrlA[4][LL];
    const int tid = threadIdx.x;
    const int wv = tid >> 6, l = tid & 63;
    const int lo = l & 7, hi = l >> 3;
    const bool isF = blockIdx.x < 4096;
    const int task = (isF ? blockIdx.x : blockIdx.x - 4096) * 4 + wv;
    const int seq = task >> 5, seg = task & 31;
    const int sb = seq * TT;
    const int t0 = seg * LL;

    for (int e = tid; e < 340; e += 256) {
        const int ss = e / 68, idx = e - ss * 68;
        float v = 0.0f;
        if (idx < 64) {
            const int row = idx >> 3, r = idx & 7;
            v = isF ? K[ss*64 + row*8 + (row ^ r)]
                    : K[ss*64 + (row ^ r)*8 + row];
        }
        kTab[e] = v;
    }
    if (l < LL) {
        const int tt = t0 + l;
        ctrlA[wv][l] = s[sb+tt] | (x[sb+tt] << 3) | ((mask[sb+tt] != 0.0f) ? 16 : 0);
    }
    __syncthreads();

    const float pL0 = P[lo*2+0], pL1 = P[lo*2+1];
    const float* kbase = kTab + lo*8;
    float av = (lo == hi) ? 1.0f : 0.0f;
    float c = 0.0f;

    if (isF) {
#pragma unroll 4
        for (int u = 0; u < LL; ++u) {
            const int cw = __builtin_amdgcn_readfirstlane(ctrlA[wv][u]);
            if (cw & 16) {
                const float* kp = kbase + (cw & 7) * 68;
                const float4 k0 = *(const float4*)kp;
                const float4 k1 = *(const float4*)(kp + 4);
                const float a0 = av;
                GATHER8(a0, a1, a2, a3, a4, a5, a6, a7)
                FMASUM(acc, k0, k1, a0,a1,a2,a3,a4,a5,a6,a7)
                av = acc * ((cw & 8) ? pL1 : pL0);
            }
            if ((u & 3) == 3) {
                const float ms = gmax8(av);
                av *= __builtin_amdgcn_rcpf(ms);
                c += __logf(ms);
            }
        }
        FM[task*64 + l] = __logf(av) + c;
    } else {
        const int t1 = t0 + LL;
        int sxc = 0;
        for (int tt = t1; tt < TT; ++tt) {
            if (mask[sb + tt] != 0.0f) { sxc = s[sb+tt] | (x[sb+tt] << 3); break; }
        }
        int m1 = (t1 < TT && mask[sb + t1] != 0.0f) ? 16 : 0;
        sxc = __builtin_amdgcn_readfirstlane(sxc);
        m1  = __builtin_amdgcn_readfirstlane(m1);
#pragma unroll 4
        for (int u = LL - 1; u >= 0; --u) {
            const int cw = __builtin_amdgcn_readfirstlane(ctrlA[wv][u]);
            if (m1) {
                const float* kp = kbase + (sxc & 7) * 68;
                const float4 k0 = *(const float4*)kp;
                const float4 k1 = *(const float4*)(kp + 4);
                const float u0 = av * ((sxc & 8) ? pL1 : pL0);
                GATHER8(u0, u1, u2, u3, u4, u5, u6, u7)
                FMASUM(acc, k0, k1, u0,u1,u2,u3,u4,u5,u6,u7)
                av = acc;
            }
            sxc = (cw & 16) ? (cw & 15) : sxc;
            m1 = cw & 16;
            if ((u & 3) == 0) {
                const float ms = gmax8(av);
                av *= __builtin_amdgcn_rcpf(ms);
                c += __logf(ms);
            }
        }
        BM[task*64 + l] = __logf(av) + c;
    }
}

// ============ Phase B: compose (R12-verified) ============
__global__ __launch_bounds__(256) void compose_kernel(
    const float* __restrict__ pi, const float* __restrict__ FM, const float* __restrict__ BM,
    float* __restrict__ SV, float* __restrict__ WV, float* __restrict__ loglik)
{
    const int tid = threadIdx.x;
    const int grp = blockIdx.x * 32 + (tid >> 3);
    const int i = tid & 7;
    if (grp < BB) {
        const int seq = grp;
        float v = __logf(pi[i]);
        for (int g = 0; g < GG; ++g) {
            SV[(seq*GG + g)*8 + i] = v;
            const float* M = FM + (size_t)(seq*GG + g) * 64;
            const float a0 = v;
            GATHER8(a0, a1, a2, a3, a4, a5, a6, a7)
            const float q0 = M[(i^0)*8 + i] + a0;
            const float q1 = M[(i^1)*8 + i] + a1;
            const float q2 = M[(i^2)*8 + i] + a2;
            const float q3 = M[(i^3)*8 + i] + a3;
            const float q4 = M[(i^4)*8 + i] + a4;
            const float q5 = M[(i^5)*8 + i] + a5;
            const float q6 = M[(i^6)*8 + i] + a6;
            const float q7 = M[(i^7)*8 + i] + a7;
            float m = fmaxf(q0, q1); m = fmaxf(m, q2); m = fmaxf(m, q3);
            m = fmaxf(m, q4); m = fmaxf(m, q5); m = fmaxf(m, q6); m = fmaxf(m, q7);
            float sum = __expf(q0-m) + __expf(q1-m) + __expf(q2-m) + __expf(q3-m)
                      + __expf(q4-m) + __expf(q5-m) + __expf(q6-m) + __expf(q7-m);
            v = m + __logf(sum);
        }
        const float gm = gmax8(v);
        const float ge = gsum8(__expf(v - gm));
        if (i == 0) loglik[seq] = gm + __logf(ge);
    } else {
        const int seq = grp - BB;
        float v = 0.0f;
        for (int g = GG - 1; g >= 0; --g) {
            WV[(seq*GG + g)*8 + i] = v;
            const float* M = BM + (size_t)(seq*GG + g) * 64;
            const float a0 = v;
            GATHER8(a0, a1, a2, a3, a4, a5, a6, a7)
            const float q0 = M[(i^0)*8 + i] + a0;
            const float q1 = M[(i^1)*8 + i] + a1;
            const float q2 = M[(i^2)*8 + i] + a2;
            const float q3 = M[(i^3)*8 + i] + a3;
            const float q4 = M[(i^4)*8 + i] + a4;
            const float q5 = M[(i^5)*8 + i] + a5;
            const float q6 = M[(i^6)*8 + i] + a6;
            const float q7 = M[(i^7)*8 + i] + a7;
            float m = fmaxf(q0, q1); m = fmaxf(m, q2); m = fmaxf(m, q3);
            m = fmaxf(m, q4); m = fmaxf(m, q5); m = fmaxf(m, q6); m = fmaxf(m, q7);
            float sum = __expf(q0-m) + __expf(q1-m) + __expf(q2-m) + __expf(q3-m)
                      + __expf(q4-m) + __expf(q5-m) + __expf(q6-m) + __expf(q7-m);
            v = m + __logf(sum);
        }
    }
}

// ============ Phase C: FUSED replay + gamma/xi ============
// block = (8-seq group) x (2 adjacent segments); 4 waves: {fwdA, bwdA, fwdB, bwdB}.
// Scans = R12 replay loops + LDS deposit; then in-block gamma/xi from LDS.
__global__ __launch_bounds__(256) void fused_kernel(
    const int* __restrict__ s, const int* __restrict__ x, const float* __restrict__ mask,
    const float* __restrict__ P, const float* __restrict__ K,
    const float* __restrict__ SV, const float* __restrict__ WV,
    const float* __restrict__ loglik,
    float* __restrict__ alpha, float* __restrict__ beta,
    float* __restrict__ gamma, float* __restrict__ xi, int skipRow0)
{
    __shared__ float aLs[2 * 32 * SROW];   // log-alpha tile
    __shared__ float bLs[2 * 33 * SROW];   // log-beta tile (+ boundary slot 32)
    __shared__ int   ctrlL[2 * 33 * 8];    // packed s|x<<3|m<<4, slot 32 = t1
    __shared__ float kX[340], kTt[340];    // xor-layout K and K^T
    __shared__ float lK[320], lP[16];      // natural-layout logK, logP

    const int tid = threadIdx.x;
    const int wv = tid >> 6, l = tid & 63;
    const int lo = l & 7, g = l >> 3;
    const int sgp = blockIdx.x >> 4;            // 64 seq-groups
    const int pairIdx = blockIdx.x & 15;        // 16 segment pairs
    const int bfirst = sgp * 8;
    const int segi = wv >> 1;                   // 0 = segA, 1 = segB
    const bool isFwd = (wv & 1) == 0;
    const int seg = pairIdx * 2 + segi;
    const int t0 = seg * LL;
    const int seq = bfirst + g;
    const int sb = seq * TT;

    // ---- stage tables + control ----
    for (int e = tid; e < 340; e += 256) {
        const int ss = e / 68, idx = e - ss * 68;
        float vX = 0.0f, vT = 0.0f;
        if (idx < 64) {
            const int row = idx >> 3, r = idx & 7;
            vX = K[ss*64 + row*8 + (row ^ r)];
            vT = K[ss*64 + (row ^ r)*8 + row];
        }
        kX[e] = vX; kTt[e] = vT;
    }
    for (int e = tid; e < 320; e += 256) lK[e] = __logf(K[e]);
    if (tid < 16) lP[tid] = __logf(P[tid]);
    for (int e = tid; e < 528; e += 256) {
        const int si = e / 264, rem = e - si * 264;
        const int u = rem >> 3, gg = rem & 7;
        const int t = (pairIdx*2 + si)*LL + u;
        int cv = 0;
        if (t < TT) {
            const int a = (bfirst + gg)*TT + t;
            cv = s[a] | (x[a] << 3) | ((mask[a] != 0.0f) ? 16 : 0);
        }
        ctrlL[(si*33 + u)*8 + gg] = cv;
    }
    __syncthreads();

    const float pL0 = P[lo*2+0], pL1 = P[lo*2+1];

    if (isFwd) {
        const float sv0 = SV[(seq*GG + seg)*8 + lo];
        const float mx = gmax8(sv0);
        float av = __expf(sv0 - mx);
        float c = mx;
        size_t aoff = (size_t)(sb + t0)*8 + lo;
#pragma unroll 4
        for (int u = 0; u < LL; ++u) {
            const int cw = ctrlL[(segi*33 + u)*8 + g];
            const float* kp = kX + (cw & 7)*68 + lo*8;
            const float4 k0 = *(const float4*)kp;
            const float4 k1 = *(const float4*)(kp + 4);
            const float a0 = av;
            GATHER8(a0, a1, a2, a3, a4, a5, a6, a7)
            FMASUM(acc, k0, k1, a0,a1,a2,a3,a4,a5,a6,a7)
            const float nv = acc * ((cw & 8) ? pL1 : pL0);
            av = (cw & 16) ? nv : av;
            if ((u & 3) == 3) {
                const float ms = gmax8(av);
                av *= __builtin_amdgcn_rcpf(ms);
                c += __logf(ms);
            }
            const float la = __logf(av) + c;
            aLs[(segi*32 + u)*SROW + g*8 + lo] = la;
            __builtin_nontemporal_store(la, &alpha[aoff]);
            aoff += 8;
        }
    } else {
        const float w0 = WV[(seq*GG + seg)*8 + lo];
        const float llv = loglik[seq];
        const float mx = gmax8(w0);
        float bv = __expf(w0 - mx);
        float c = mx - llv;
        bLs[(segi*33 + 32)*SROW + g*8 + lo] = w0 - llv;   // normalized beta[t1]
        const int t1 = t0 + LL;
        int m1 = ctrlL[(segi*33 + 32)*8 + g] & 16;
        int sxc = 0;
        {   // per-group bounded search for first masked index >= t1 (R12-verified)
            int tt = t1;
            int found = (t1 >= TT) ? 1 : 0;
            while (!__all(found)) {
                if (!found && tt < TT) {
                    if (mask[sb + tt] != 0.0f) { sxc = s[sb+tt] | (x[sb+tt] << 3); found = 1; }
                }
                if (tt >= TT - 1) found = 1;
                ++tt;
            }
        }
        size_t boff = (size_t)(sb + t1 - 1)*8 + lo;
#pragma unroll 4
        for (int u = LL - 1; u >= 0; --u) {
            const int cw = ctrlL[(segi*33 + u)*8 + g];
            const float* kp = kTt + (sxc & 7)*68 + lo*8;
            const float4 k0 = *(const float4*)kp;
            const float4 k1 = *(const float4*)(kp + 4);
            const float u0 = bv * ((sxc & 8) ? pL1 : pL0);
            GATHER8(u0, u1, u2, u3, u4, u5, u6, u7)
            FMASUM(acc, k0, k1, u0,u1,u2,u3,u4,u5,u6,u7)
            bv = m1 ? acc : bv;
            if ((u & 3) == 0) {
                const float ms = gmax8(bv);
                bv *= __builtin_amdgcn_rcpf(ms);
                c += __logf(ms);
            }
            const float lb = __logf(bv) + c;
            bLs[(segi*33 + u)*SROW + g*8 + lo] = lb;
            __builtin_nontemporal_store(lb, &beta[boff]);
            boff -= 8;
            sxc = (cw & 16) ? (cw & 15) : sxc;
            m1 = cw & 16;
        }
    }
    __syncthreads();

    // ---- gamma: 512 rows / block, 8 rows per wave-iteration ----
    for (int it = 0; it < 16; ++it) {
        const int r = wv*128 + it*8 + (l >> 3);
        const int si = r >> 8, rr = r & 255, sq = rr >> 5, u = rr & 31;
        const int t = (pairIdx*2 + si)*LL + u;
        const int z = l & 7;
        const int cw = ctrlL[(si*33 + u)*8 + sq];
        const float gv = (cw & 16)
            ? (aLs[(si*32 + u)*SROW + sq*8 + z] + bLs[(si*33 + u)*SROW + sq*8 + z])
            : NINF;
        __builtin_nontemporal_store(gv, &gamma[((size_t)(bfirst+sq)*TT + t)*8 + z]);
    }
    // ---- xi: 512 rows / block, 1 row (64 lanes) per wave-iteration ----
    for (int it = 0; it < 128; ++it) {
        const int r = wv*128 + it;
        const int si = r >> 8, rr = r & 255, sq = rr >> 5, u = rr & 31;
        const int t = (pairIdx*2 + si)*LL + u;
        if (t >= TT - 1) continue;
        const int rowLin = (bfirst + sq)*(TT - 1) + t;
        if (rowLin >= skipRow0) continue;          // xi-tail scratch protection
        const int cw  = ctrlL[(si*33 + u)*8 + sq];
        const int cw1 = ctrlL[(si*33 + u + 1)*8 + sq];
        float xo = NINF;
        if (cw1 & 16) {
            const float aHi = aLs[(si*32 + u)*SROW + sq*8 + (l >> 3)];
            const float bN  = bLs[(si*33 + u + 1)*SROW + sq*8 + (l & 7)];
            xo = lK[(cw & 7)*64 + l] + aHi + bN + lP[(l & 7)*2 + ((cw1 >> 3) & 1)];
        }
        __builtin_nontemporal_store(xo, &xi[(size_t)rowLin*64 + l]);
    }
}

// ============ xi tail fixup (only when scratch lives in xi's tail) ============
__global__ __launch_bounds__(256) void xi_fixup_kernel(
    const int* __restrict__ s, const int* __restrict__ x, const float* __restrict__ mask,
    const float* __restrict__ P, const float* __restrict__ K,
    const float* __restrict__ alpha, const float* __restrict__ beta,
    float* __restrict__ xi)
{
    __shared__ float lK[320], lP[16];
    const int tid = threadIdx.x;
    for (int e = tid; e < 320; e += 256) lK[e] = __logf(K[e]);
    if (tid < 16) lP[tid] = __logf(P[tid]);
    __syncthreads();

    const int wv = tid >> 6, l = tid & 63;
    const int row = SCRATCH_ROW0 + blockIdx.x * 4 + wv;
    if (row >= NXROWS) return;
    const int b = row / (TT - 1);
    const int t = row - b * (TT - 1);
    const long bt = (long)b * TT + t;
    float xo = NINF;
    if (mask[bt + 1] != 0.0f) {
        const int sv = s[bt];
        const int xv = x[bt + 1];
        const float aHi = alpha[bt*8 + (l >> 3)];
        const float bN  = beta[(bt + 1)*8 + (l & 7)];
        xo = lK[sv*64 + l] + aHi + bN + lP[(l & 7)*2 + xv];
    }
    xi[(size_t)row*64 + l] = xo;
}

extern "C" void kernel_launch(void* const* d_in, const int* in_sizes, int n_in,
                              void* d_out, int out_size, void* d_ws, size_t ws_size,
                              hipStream_t stream) {
    const int*   s    = (const int*)d_in[0];
    const int*   x    = (const int*)d_in[1];
    const float* mask = (const float*)d_in[2];
    const float* pi   = (const float*)d_in[3];
    const float* P    = (const float*)d_in[4];
    const float* K    = (const float*)d_in[5];

    float* out    = (float*)d_out;
    float* gamma  = out;                                  // (B,T,Z)
    float* xi     = gamma + (size_t)BB * TT * 8;          // (B,T-1,Z,Z)
    float* alpha  = xi + (size_t)BB * (TT - 1) * 64;      // (B,T,Z)
    float* beta   = alpha + (size_t)BB * TT * 8;          // (B,T,Z)
    float* loglik = beta + (size_t)BB * TT * 8;           // (B,)

    const size_t scratchFloats = (size_t)2*BB*GG*64 + (size_t)2*BB*GG*8;  // FM,BM,SV,WV
    const bool useWs = ws_size >= scratchFloats * sizeof(float);
    float* FMs = useWs ? (float*)d_ws : xi + (size_t)31000000;
    float* BMs = FMs + (size_t)BB * GG * 64;
    float* SVs = BMs + (size_t)BB * GG * 64;
    float* WVs = SVs + (size_t)BB * GG * 8;
    const int skipRow0 = useWs ? 0x7FFFFFFF : SCRATCH_ROW0;

    segmat_kernel<<<8192, 256, 0, stream>>>(s, x, mask, P, K, FMs, BMs);
    compose_kernel<<<32, 256, 0, stream>>>(pi, FMs, BMs, SVs, WVs, loglik);
    fused_kernel<<<1024, 256, 0, stream>>>(s, x, mask, P, K, SVs, WVs, loglik,
                                           alpha, beta, gamma, xi, skipRow0);
    if (!useWs) {
        const int tailRows = NXROWS - SCRATCH_ROW0;
        xi_fixup_kernel<<<(tailRows + 3) / 4, 256, 0, stream>>>(
            s, x, mask, P, K, alpha, beta, xi);
    }
}

// Round 14
// 110.137 us; speedup vs baseline: 1.4350x; 1.1368x over previous
//
#include <hip/hip_runtime.h>

#define BB 512
#define TT 1024
#define GG 32
#define LL 32
#define NINF -10000000000.0f
#define SROW 68                 // LDS row stride (floats): mult of 4 for b128 alignment
#define NXROWS (BB * (TT - 1))  // 523776 xi rows
#define SCRATCH_ROW0 484375     // xi row where xi-tail scratch begins (31,000,000/64)

typedef float fvec4 __attribute__((ext_vector_type(4)));

// DPP ctrls: quad_perm xor1=0xB1, xor2=0x4E; row_half_mirror(^7)=0x141
template<int CTRL>
__device__ __forceinline__ float dppf(float x) {
    return __builtin_bit_cast(float, __builtin_amdgcn_update_dpp(
        0, __builtin_bit_cast(int, x), CTRL, 0xF, 0xF, true));
}
__device__ __forceinline__ float gsum8(float x) {
    x += dppf<0xB1>(x); x += dppf<0x4E>(x); x += dppf<0x141>(x); return x;
}
__device__ __forceinline__ float gmax8(float x) {
    x = fmaxf(x, dppf<0xB1>(x)); x = fmaxf(x, dppf<0x4E>(x)); x = fmaxf(x, dppf<0x141>(x)); return x;
}

#define GATHER8(A0, A1, A2, A3, A4, A5, A6, A7)      \
    const float A1 = dppf<0xB1>(A0);                 \
    const float A2 = dppf<0x4E>(A0);                 \
    const float A7 = dppf<0x141>(A0);                \
    const float A3 = dppf<0x4E>(A1);                 \
    const float A6 = dppf<0xB1>(A7);                 \
    const float A5 = dppf<0x4E>(A7);                 \
    const float A4 = dppf<0x4E>(A6);

#define FMASUM(ACC, K0, K1, A0,A1,A2,A3,A4,A5,A6,A7) \
    float ACC;                                       \
    {   float accA = K0.x * A0;                      \
        accA = fmaf(K0.y, A1, accA);                 \
        accA = fmaf(K0.z, A2, accA);                 \
        accA = fmaf(K0.w, A3, accA);                 \
        float accB = K1.x * A4;                      \
        accB = fmaf(K1.y, A5, accB);                 \
        accB = fmaf(K1.z, A6, accB);                 \
        ACC = accA + accB; }

// ============ Phase A: per-segment 8x8 transfer matrices (R12-verified) ============
__global__ __launch_bounds__(256) void segmat_kernel(
    const int* __restrict__ s, const int* __restrict__ x, const float* __restrict__ mask,
    const float* __restrict__ P, const float* __restrict__ K,
    float* __restrict__ FM, float* __restrict__ BM)
{
    __shared__ float kTab[5 * 68];
    __shared__ int   ctrlA[4][LL];
    const int tid = threadIdx.x;
    const int wv = tid >> 6, l = tid & 63;
    const int lo = l & 7, hi = l >> 3;
    const bool isF = blockIdx.x < 4096;
    const int task = (isF ? blockIdx.x : blockIdx.x - 4096) * 4 + wv;
    const int seq = task >> 5, seg = task & 31;
    const int sb = seq * TT;
    const int t0 = seg * LL;

    for (int e = tid; e < 340; e += 256) {
        const int ss = e / 68, idx = e - ss * 68;
        float v = 0.0f;
        if (idx < 64) {
            const int row = idx >> 3, r = idx & 7;
            v = isF ? K[ss*64 + row*8 + (row ^ r)]
                    : K[ss*64 + (row ^ r)*8 + row];
        }
        kTab[e] = v;
    }
    if (l < LL) {
        const int tt = t0 + l;
        ctrlA[wv][l] = s[sb+tt] | (x[sb+tt] << 3) | ((mask[sb+tt] != 0.0f) ? 16 : 0);
    }
    __syncthreads();

    const float pL0 = P[lo*2+0], pL1 = P[lo*2+1];
    const float* kbase = kTab + lo*8;
    float av = (lo == hi) ? 1.0f : 0.0f;
    float c = 0.0f;

    if (isF) {
#pragma unroll 4
        for (int u = 0; u < LL; ++u) {
            const int cw = __builtin_amdgcn_readfirstlane(ctrlA[wv][u]);
            if (cw & 16) {
                const float* kp = kbase + (cw & 7) * 68;
                const float4 k0 = *(const float4*)kp;
                const float4 k1 = *(const float4*)(kp + 4);
                const float a0 = av;
                GATHER8(a0, a1, a2, a3, a4, a5, a6, a7)
                FMASUM(acc, k0, k1, a0,a1,a2,a3,a4,a5,a6,a7)
                av = acc * ((cw & 8) ? pL1 : pL0);
            }
            if ((u & 3) == 3) {
                const float ms = gmax8(av);
                av *= __builtin_amdgcn_rcpf(ms);
                c += __logf(ms);
            }
        }
        FM[task*64 + l] = __logf(av) + c;
    } else {
        const int t1 = t0 + LL;
        int sxc = 0;
        for (int tt = t1; tt < TT; ++tt) {
            if (mask[sb + tt] != 0.0f) { sxc = s[sb+tt] | (x[sb+tt] << 3); break; }
        }
        int m1 = (t1 < TT && mask[sb + t1] != 0.0f) ? 16 : 0;
        sxc = __builtin_amdgcn_readfirstlane(sxc);
        m1  = __builtin_amdgcn_readfirstlane(m1);
#pragma unroll 4
        for (int u = LL - 1; u >= 0; --u) {
            const int cw = __builtin_amdgcn_readfirstlane(ctrlA[wv][u]);
            if (m1) {
                const float* kp = kbase + (sxc & 7) * 68;
                const float4 k0 = *(const float4*)kp;
                const float4 k1 = *(const float4*)(kp + 4);
                const float u0 = av * ((sxc & 8) ? pL1 : pL0);
                GATHER8(u0, u1, u2, u3, u4, u5, u6, u7)
                FMASUM(acc, k0, k1, u0,u1,u2,u3,u4,u5,u6,u7)
                av = acc;
            }
            sxc = (cw & 16) ? (cw & 15) : sxc;
            m1 = cw & 16;
            if ((u & 3) == 0) {
                const float ms = gmax8(av);
                av *= __builtin_amdgcn_rcpf(ms);
                c += __logf(ms);
            }
        }
        BM[task*64 + l] = __logf(av) + c;
    }
}

// ============ Phase B: compose (R12-verified) ============
__global__ __launch_bounds__(256) void compose_kernel(
    const float* __restrict__ pi, const float* __restrict__ FM, const float* __restrict__ BM,
    float* __restrict__ SV, float* __restrict__ WV, float* __restrict__ loglik)
{
    const int tid = threadIdx.x;
    const int grp = blockIdx.x * 32 + (tid >> 3);
    const int i = tid & 7;
    if (grp < BB) {
        const int seq = grp;
        float v = __logf(pi[i]);
        for (int g = 0; g < GG; ++g) {
            SV[(seq*GG + g)*8 + i] = v;
            const float* M = FM + (size_t)(seq*GG + g) * 64;
            const float a0 = v;
            GATHER8(a0, a1, a2, a3, a4, a5, a6, a7)
            const float q0 = M[(i^0)*8 + i] + a0;
            const float q1 = M[(i^1)*8 + i] + a1;
            const float q2 = M[(i^2)*8 + i] + a2;
            const float q3 = M[(i^3)*8 + i] + a3;
            const float q4 = M[(i^4)*8 + i] + a4;
            const float q5 = M[(i^5)*8 + i] + a5;
            const float q6 = M[(i^6)*8 + i] + a6;
            const float q7 = M[(i^7)*8 + i] + a7;
            float m = fmaxf(q0, q1); m = fmaxf(m, q2); m = fmaxf(m, q3);
            m = fmaxf(m, q4); m = fmaxf(m, q5); m = fmaxf(m, q6); m = fmaxf(m, q7);
            float sum = __expf(q0-m) + __expf(q1-m) + __expf(q2-m) + __expf(q3-m)
                      + __expf(q4-m) + __expf(q5-m) + __expf(q6-m) + __expf(q7-m);
            v = m + __logf(sum);
        }
        const float gm = gmax8(v);
        const float ge = gsum8(__expf(v - gm));
        if (i == 0) loglik[seq] = gm + __logf(ge);
    } else {
        const int seq = grp - BB;
        float v = 0.0f;
        for (int g = GG - 1; g >= 0; --g) {
            WV[(seq*GG + g)*8 + i] = v;
            const float* M = BM + (size_t)(seq*GG + g) * 64;
            const float a0 = v;
            GATHER8(a0, a1, a2, a3, a4, a5, a6, a7)
            const float q0 = M[(i^0)*8 + i] + a0;
            const float q1 = M[(i^1)*8 + i] + a1;
            const float q2 = M[(i^2)*8 + i] + a2;
            const float q3 = M[(i^3)*8 + i] + a3;
            const float q4 = M[(i^4)*8 + i] + a4;
            const float q5 = M[(i^5)*8 + i] + a5;
            const float q6 = M[(i^6)*8 + i] + a6;
            const float q7 = M[(i^7)*8 + i] + a7;
            float m = fmaxf(q0, q1); m = fmaxf(m, q2); m = fmaxf(m, q3);
            m = fmaxf(m, q4); m = fmaxf(m, q5); m = fmaxf(m, q6); m = fmaxf(m, q7);
            float sum = __expf(q0-m) + __expf(q1-m) + __expf(q2-m) + __expf(q3-m)
                      + __expf(q4-m) + __expf(q5-m) + __expf(q6-m) + __expf(q7-m);
            v = m + __logf(sum);
        }
    }
}

// ============ Phase C: FUSED replay + all-output bulk write ============
// block = (8-seq group) x (2 adjacent segments); 4 waves: {fwdA, bwdA, fwdB, bwdB}.
// Scans write LDS only; barrier; then coalesced float4 nt writes of alpha/beta/gamma/xi.
__global__ __launch_bounds__(256) void fused_kernel(
    const int* __restrict__ s, const int* __restrict__ x, const float* __restrict__ mask,
    const float* __restrict__ P, const float* __restrict__ K,
    const float* __restrict__ SV, const float* __restrict__ WV,
    const float* __restrict__ loglik,
    float* __restrict__ alpha, float* __restrict__ beta,
    float* __restrict__ gamma, float* __restrict__ xi, int skipRow0)
{
    __shared__ float aLs[2 * 32 * SROW];   // log-alpha tile
    __shared__ float bLs[2 * 33 * SROW];   // log-beta tile (+ boundary slot 32 per seg)
    __shared__ int   ctrlL[2 * 33 * 8];    // packed s|x<<3|m<<4, slot 32 = t1
    __shared__ float kX[340], kTt[340];    // xor-layout K and K^T
    __shared__ float lK[320];              // natural-layout logK
    __shared__ float lP0[8], lP1[8];

    const int tid = threadIdx.x;
    const int wv = tid >> 6, l = tid & 63;
    const int lo = l & 7, g = l >> 3;
    const int sgp = blockIdx.x >> 4;            // 64 seq-groups
    const int pairIdx = blockIdx.x & 15;        // 16 segment pairs
    const int bfirst = sgp * 8;
    const int segi = wv >> 1;                   // 0 = segA, 1 = segB
    const bool isFwd = (wv & 1) == 0;
    const int seg = pairIdx * 2 + segi;
    const int t0 = seg * LL;
    const int seq = bfirst + g;
    const int sb = seq * TT;

    // ---- stage tables + control ----
    for (int e = tid; e < 340; e += 256) {
        const int ss = e / 68, idx = e - ss * 68;
        float vX = 0.0f, vT = 0.0f;
        if (idx < 64) {
            const int row = idx >> 3, r = idx & 7;
            vX = K[ss*64 + row*8 + (row ^ r)];
            vT = K[ss*64 + (row ^ r)*8 + row];
        }
        kX[e] = vX; kTt[e] = vT;
    }
    for (int e = tid; e < 320; e += 256) lK[e] = __logf(K[e]);
    if (tid < 8) { lP0[tid] = __logf(P[tid*2]); lP1[tid] = __logf(P[tid*2+1]); }
    for (int e = tid; e < 528; e += 256) {
        const int si = e / 264, rem = e - si * 264;
        const int u = rem >> 3, gg = rem & 7;
        const int t = (pairIdx*2 + si)*LL + u;
        int cv = 0;
        if (t < TT) {
            const int a = (bfirst + gg)*TT + t;
            cv = s[a] | (x[a] << 3) | ((mask[a] != 0.0f) ? 16 : 0);
        }
        ctrlL[(si*33 + u)*8 + gg] = cv;
    }
    __syncthreads();

    const float pL0 = P[lo*2+0], pL1 = P[lo*2+1];

    if (isFwd) {
        const float sv0 = SV[(seq*GG + seg)*8 + lo];
        const float mx = gmax8(sv0);
        float av = __expf(sv0 - mx);
        float c = mx;
#pragma unroll 4
        for (int u = 0; u < LL; ++u) {
            const int cw = ctrlL[(segi*33 + u)*8 + g];
            const float* kp = kX + (cw & 7)*68 + lo*8;
            const float4 k0 = *(const float4*)kp;
            const float4 k1 = *(const float4*)(kp + 4);
            const float a0 = av;
            GATHER8(a0, a1, a2, a3, a4, a5, a6, a7)
            FMASUM(acc, k0, k1, a0,a1,a2,a3,a4,a5,a6,a7)
            const float nv = acc * ((cw & 8) ? pL1 : pL0);
            av = (cw & 16) ? nv : av;
            if ((u & 3) == 3) {
                const float ms = gmax8(av);
                av *= __builtin_amdgcn_rcpf(ms);
                c += __logf(ms);
            }
            aLs[(segi*32 + u)*SROW + g*8 + lo] = __logf(av) + c;
        }
    } else {
        const float w0 = WV[(seq*GG + seg)*8 + lo];
        const float llv = loglik[seq];
        const float mx = gmax8(w0);
        float bv = __expf(w0 - mx);
        float c = mx - llv;
        bLs[(segi*33 + 32)*SROW + g*8 + lo] = w0 - llv;   // normalized beta[t1]
        const int t1 = t0 + LL;
        int m1 = ctrlL[(segi*33 + 32)*8 + g] & 16;
        int sxc = 0;
        {   // per-group bounded search for first masked index >= t1 (R12-verified)
            int tt = t1;
            int found = (t1 >= TT) ? 1 : 0;
            while (!__all(found)) {
                if (!found && tt < TT) {
                    if (mask[sb + tt] != 0.0f) { sxc = s[sb+tt] | (x[sb+tt] << 3); found = 1; }
                }
                if (tt >= TT - 1) found = 1;
                ++tt;
            }
        }
#pragma unroll 4
        for (int u = LL - 1; u >= 0; --u) {
            const int cw = ctrlL[(segi*33 + u)*8 + g];
            const float* kp = kTt + (sxc & 7)*68 + lo*8;
            const float4 k0 = *(const float4*)kp;
            const float4 k1 = *(const float4*)(kp + 4);
            const float u0 = bv * ((sxc & 8) ? pL1 : pL0);
            GATHER8(u0, u1, u2, u3, u4, u5, u6, u7)
            FMASUM(acc, k0, k1, u0,u1,u2,u3,u4,u5,u6,u7)
            bv = m1 ? acc : bv;
            if ((u & 3) == 0) {
                const float ms = gmax8(bv);
                bv *= __builtin_amdgcn_rcpf(ms);
                c += __logf(ms);
            }
            bLs[(segi*33 + u)*SROW + g*8 + lo] = __logf(bv) + c;
            sxc = (cw & 16) ? (cw & 15) : sxc;
            m1 = cw & 16;
        }
    }
    __syncthreads();

    // ---- bulk coalesced write phase ----
    const int t0base = pairIdx * 64;
    // alpha / beta / gamma: 4096 floats each = 1024 float4 -> 4 iters
    for (int it = 0; it < 4; ++it) {
        const int f4 = it*256 + tid;            // [0,1024)
        const int sq = f4 >> 7;                 // 128 float4 per seq
        const int rem = f4 & 127;
        const int tl = rem >> 1, z4 = (rem & 1) * 4;
        const int si = tl >> 5, u = tl & 31;
        const size_t gbase = ((size_t)(bfirst+sq)*TT + t0base + tl)*8 + z4;
        const float4 av4 = *(const float4*)&aLs[(si*32+u)*SROW + sq*8 + z4];
        const float4 bv4 = *(const float4*)&bLs[(si*33+u)*SROW + sq*8 + z4];
        __builtin_nontemporal_store(__builtin_bit_cast(fvec4, av4), (fvec4*)&alpha[gbase]);
        __builtin_nontemporal_store(__builtin_bit_cast(fvec4, bv4), (fvec4*)&beta[gbase]);
        float4 gv;
        if (ctrlL[(si*33+u)*8 + sq] & 16) {
            gv.x = av4.x + bv4.x; gv.y = av4.y + bv4.y;
            gv.z = av4.z + bv4.z; gv.w = av4.w + bv4.w;
        } else { gv.x = NINF; gv.y = NINF; gv.z = NINF; gv.w = NINF; }
        __builtin_nontemporal_store(__builtin_bit_cast(fvec4, gv), (fvec4*)&gamma[gbase]);
    }
    // xi: 512 rows x 16 float4 = 8192 float4 -> 32 iters
    for (int it = 0; it < 32; ++it) {
        const int f4 = it*256 + tid;
        const int r = f4 >> 4, ll2 = f4 & 15;
        const int sq = r >> 6, tl = r & 63;
        const int t = t0base + tl;
        if (t >= TT - 1) continue;
        const int rowLin = (bfirst + sq)*(TT - 1) + t;
        if (rowLin >= skipRow0) continue;          // xi-tail scratch protection
        const int si = tl >> 5, u = tl & 31;
        const int cw  = ctrlL[(si*33 + u)*8 + sq];
        const int cw1 = ctrlL[(si*33 + u + 1)*8 + sq];
        float4 o;
        if (cw1 & 16) {
            const int i = ll2 >> 1, bj = (ll2 & 1)*4;
            const float aHi = aLs[(si*32 + u)*SROW + sq*8 + i];
            const float4 bN = *(const float4*)&bLs[(si*33 + u + 1)*SROW + sq*8 + bj];
            const float4 kv = *(const float4*)&lK[(cw & 7)*64 + ll2*4];
            const float4 p0 = *(const float4*)&lP0[bj];
            const float4 p1 = *(const float4*)&lP1[bj];
            const int xv = (cw1 >> 3) & 1;
            o.x = kv.x + aHi + bN.x + (xv ? p1.x : p0.x);
            o.y = kv.y + aHi + bN.y + (xv ? p1.y : p0.y);
            o.z = kv.z + aHi + bN.z + (xv ? p1.z : p0.z);
            o.w = kv.w + aHi + bN.w + (xv ? p1.w : p0.w);
        } else { o.x = NINF; o.y = NINF; o.z = NINF; o.w = NINF; }
        __builtin_nontemporal_store(__builtin_bit_cast(fvec4, o),
                                    (fvec4*)&xi[(size_t)rowLin*64 + ll2*4]);
    }
}

// ============ xi tail fixup (only when scratch lives in xi's tail) ============
__global__ __launch_bounds__(256) void xi_fixup_kernel(
    const int* __restrict__ s, const int* __restrict__ x, const float* __restrict__ mask,
    const float* __restrict__ P, const float* __restrict__ K,
    const float* __restrict__ alpha, const float* __restrict__ beta,
    float* __restrict__ xi)
{
    __shared__ float lK[320], lP[16];
    const int tid = threadIdx.x;
    for (int e = tid; e < 320; e += 256) lK[e] = __logf(K[e]);
    if (tid < 16) lP[tid] = __logf(P[tid]);
    __syncthreads();

    const int wv = tid >> 6, l = tid & 63;
    const int row = SCRATCH_ROW0 + blockIdx.x * 4 + wv;
    if (row >= NXROWS) return;
    const int b = row / (TT - 1);
    const int t = row - b * (TT - 1);
    const long bt = (long)b * TT + t;
    float xo = NINF;
    if (mask[bt + 1] != 0.0f) {
        const int sv = s[bt];
        const int xv = x[bt + 1];
        const float aHi = alpha[bt*8 + (l >> 3)];
        const float bN  = beta[(bt + 1)*8 + (l & 7)];
        xo = lK[sv*64 + l] + aHi + bN + lP[(l & 7)*2 + xv];
    }
    xi[(size_t)row*64 + l] = xo;
}

extern "C" void kernel_launch(void* const* d_in, const int* in_sizes, int n_in,
                              void* d_out, int out_size, void* d_ws, size_t ws_size,
                              hipStream_t stream) {
    const int*   s    = (const int*)d_in[0];
    const int*   x    = (const int*)d_in[1];
    const float* mask = (const float*)d_in[2];
    const float* pi   = (const float*)d_in[3];
    const float* P    = (const float*)d_in[4];
    const float* K    = (const float*)d_in[5];

    float* out    = (float*)d_out;
    float* gamma  = out;                                  // (B,T,Z)
    float* xi     = gamma + (size_t)BB * TT * 8;          // (B,T-1,Z,Z)
    float* alpha  = xi + (size_t)BB * (TT - 1) * 64;      // (B,T,Z)
    float* beta   = alpha + (size_t)BB * TT * 8;          // (B,T,Z)
    float* loglik = beta + (size_t)BB * TT * 8;           // (B,)

    const size_t scratchFloats = (size_t)2*BB*GG*64 + (size_t)2*BB*GG*8;  // FM,BM,SV,WV
    const bool useWs = ws_size >= scratchFloats * sizeof(float);
    float* FMs = useWs ? (float*)d_ws : xi + (size_t)31000000;
    float* BMs = FMs + (size_t)BB * GG * 64;
    float* SVs = BMs + (size_t)BB * GG * 64;
    float* WVs = SVs + (size_t)BB * GG * 8;
    const int skipRow0 = useWs ? 0x7FFFFFFF : SCRATCH_ROW0;

    segmat_kernel<<<8192, 256, 0, stream>>>(s, x, mask, P, K, FMs, BMs);
    compose_kernel<<<32, 256, 0, stream>>>(pi, FMs, BMs, SVs, WVs, loglik);
    fused_kernel<<<1024, 256, 0, stream>>>(s, x, mask, P, K, SVs, WVs, loglik,
                                           alpha, beta, gamma, xi, skipRow0);
    if (!useWs) {
        const int tailRows = NXROWS - SCRATCH_ROW0;
        xi_fixup_kernel<<<(tailRows + 3) / 4, 256, 0, stream>>>(
            s, x, mask, P, K, alpha, beta, xi);
    }
}

// Round 15
// 107.674 us; speedup vs baseline: 1.4679x; 1.0229x over previous
//
#include <hip/hip_runtime.h>

#define BB 512
#define TT 1024
#define GG 32
#define LL 32
#define NINF -10000000000.0f
#define SROW 68                 // LDS row stride (floats): mult of 4 for b128 alignment
#define NXROWS (BB * (TT - 1))  // 523776 xi rows
#define SCRATCH_ROW0 484375     // xi row where xi-tail scratch begins (31,000,000/64)

typedef float fvec4 __attribute__((ext_vector_type(4)));

// DPP ctrls: quad_perm xor1=0xB1, xor2=0x4E; row_half_mirror(^7)=0x141
template<int CTRL>
__device__ __forceinline__ float dppf(float x) {
    return __builtin_bit_cast(float, __builtin_amdgcn_update_dpp(
        0, __builtin_bit_cast(int, x), CTRL, 0xF, 0xF, true));
}
__device__ __forceinline__ float gsum8(float x) {
    x += dppf<0xB1>(x); x += dppf<0x4E>(x); x += dppf<0x141>(x); return x;
}
__device__ __forceinline__ float gmax8(float x) {
    x = fmaxf(x, dppf<0xB1>(x)); x = fmaxf(x, dppf<0x4E>(x)); x = fmaxf(x, dppf<0x141>(x)); return x;
}

#define GATHER8(A0, A1, A2, A3, A4, A5, A6, A7)      \
    const float A1 = dppf<0xB1>(A0);                 \
    const float A2 = dppf<0x4E>(A0);                 \
    const float A7 = dppf<0x141>(A0);                \
    const float A3 = dppf<0x4E>(A1);                 \
    const float A6 = dppf<0xB1>(A7);                 \
    const float A5 = dppf<0x4E>(A7);                 \
    const float A4 = dppf<0x4E>(A6);

#define FMASUM(ACC, K0, K1, A0,A1,A2,A3,A4,A5,A6,A7) \
    float ACC;                                       \
    {   float accA = K0.x * A0;                      \
        accA = fmaf(K0.y, A1, accA);                 \
        accA = fmaf(K0.z, A2, accA);                 \
        accA = fmaf(K0.w, A3, accA);                 \
        float accB = K1.x * A4;                      \
        accB = fmaf(K1.y, A5, accB);                 \
        accB = fmaf(K1.z, A6, accB);                 \
        ACC = accA + accB; }

// ============ Phase A: per-segment 8x8 transfer matrices ============
// (R12-verified structure; rescale cadence 4->8 steps — log-bookkeeping exact)
__global__ __launch_bounds__(256) void segmat_kernel(
    const int* __restrict__ s, const int* __restrict__ x, const float* __restrict__ mask,
    const float* __restrict__ P, const float* __restrict__ K,
    float* __restrict__ FM, float* __restrict__ BM)
{
    __shared__ float kTab[5 * 68];
    __shared__ int   ctrlA[4][LL];
    const int tid = threadIdx.x;
    const int wv = tid >> 6, l = tid & 63;
    const int lo = l & 7, hi = l >> 3;
    const bool isF = blockIdx.x < 4096;
    const int task = (isF ? blockIdx.x : blockIdx.x - 4096) * 4 + wv;
    const int seq = task >> 5, seg = task & 31;
    const int sb = seq * TT;
    const int t0 = seg * LL;

    for (int e = tid; e < 340; e += 256) {
        const int ss = e / 68, idx = e - ss * 68;
        float v = 0.0f;
        if (idx < 64) {
            const int row = idx >> 3, r = idx & 7;
            v = isF ? K[ss*64 + row*8 + (row ^ r)]
                    : K[ss*64 + (row ^ r)*8 + row];
        }
        kTab[e] = v;
    }
    if (l < LL) {
        const int tt = t0 + l;
        ctrlA[wv][l] = s[sb+tt] | (x[sb+tt] << 3) | ((mask[sb+tt] != 0.0f) ? 16 : 0);
    }
    __syncthreads();

    const float pL0 = P[lo*2+0], pL1 = P[lo*2+1];
    const float* kbase = kTab + lo*8;
    float av = (lo == hi) ? 1.0f : 0.0f;
    float c = 0.0f;

    if (isF) {
#pragma unroll 8
        for (int u = 0; u < LL; ++u) {
            const int cw = __builtin_amdgcn_readfirstlane(ctrlA[wv][u]);
            if (cw & 16) {
                const float* kp = kbase + (cw & 7) * 68;
                const float4 k0 = *(const float4*)kp;
                const float4 k1 = *(const float4*)(kp + 4);
                const float a0 = av;
                GATHER8(a0, a1, a2, a3, a4, a5, a6, a7)
                FMASUM(acc, k0, k1, a0,a1,a2,a3,a4,a5,a6,a7)
                av = acc * ((cw & 8) ? pL1 : pL0);
            }
            if ((u & 7) == 7) {
                const float ms = gmax8(av);
                av *= __builtin_amdgcn_rcpf(ms);
                c += __logf(ms);
            }
        }
        FM[task*64 + l] = __logf(av) + c;
    } else {
        const int t1 = t0 + LL;
        int sxc = 0;
        for (int tt = t1; tt < TT; ++tt) {
            if (mask[sb + tt] != 0.0f) { sxc = s[sb+tt] | (x[sb+tt] << 3); break; }
        }
        int m1 = (t1 < TT && mask[sb + t1] != 0.0f) ? 16 : 0;
        sxc = __builtin_amdgcn_readfirstlane(sxc);
        m1  = __builtin_amdgcn_readfirstlane(m1);
#pragma unroll 8
        for (int u = LL - 1; u >= 0; --u) {
            const int cw = __builtin_amdgcn_readfirstlane(ctrlA[wv][u]);
            if (m1) {
                const float* kp = kbase + (sxc & 7) * 68;
                const float4 k0 = *(const float4*)kp;
                const float4 k1 = *(const float4*)(kp + 4);
                const float u0 = av * ((sxc & 8) ? pL1 : pL0);
                GATHER8(u0, u1, u2, u3, u4, u5, u6, u7)
                FMASUM(acc, k0, k1, u0,u1,u2,u3,u4,u5,u6,u7)
                av = acc;
            }
            sxc = (cw & 16) ? (cw & 15) : sxc;
            m1 = cw & 16;
            if ((u & 7) == 0) {
                const float ms = gmax8(av);
                av *= __builtin_amdgcn_rcpf(ms);
                c += __logf(ms);
            }
        }
        BM[task*64 + l] = __logf(av) + c;
    }
}

// ============ Phase B: compose (R12-verified) ============
__global__ __launch_bounds__(256) void compose_kernel(
    const float* __restrict__ pi, const float* __restrict__ FM, const float* __restrict__ BM,
    float* __restrict__ SV, float* __restrict__ WV, float* __restrict__ loglik)
{
    const int tid = threadIdx.x;
    const int grp = blockIdx.x * 32 + (tid >> 3);
    const int i = tid & 7;
    if (grp < BB) {
        const int seq = grp;
        float v = __logf(pi[i]);
        for (int g = 0; g < GG; ++g) {
            SV[(seq*GG + g)*8 + i] = v;
            const float* M = FM + (size_t)(seq*GG + g) * 64;
            const float a0 = v;
            GATHER8(a0, a1, a2, a3, a4, a5, a6, a7)
            const float q0 = M[(i^0)*8 + i] + a0;
            const float q1 = M[(i^1)*8 + i] + a1;
            const float q2 = M[(i^2)*8 + i] + a2;
            const float q3 = M[(i^3)*8 + i] + a3;
            const float q4 = M[(i^4)*8 + i] + a4;
            const float q5 = M[(i^5)*8 + i] + a5;
            const float q6 = M[(i^6)*8 + i] + a6;
            const float q7 = M[(i^7)*8 + i] + a7;
            float m = fmaxf(q0, q1); m = fmaxf(m, q2); m = fmaxf(m, q3);
            m = fmaxf(m, q4); m = fmaxf(m, q5); m = fmaxf(m, q6); m = fmaxf(m, q7);
            float sum = __expf(q0-m) + __expf(q1-m) + __expf(q2-m) + __expf(q3-m)
                      + __expf(q4-m) + __expf(q5-m) + __expf(q6-m) + __expf(q7-m);
            v = m + __logf(sum);
        }
        const float gm = gmax8(v);
        const float ge = gsum8(__expf(v - gm));
        if (i == 0) loglik[seq] = gm + __logf(ge);
    } else {
        const int seq = grp - BB;
        float v = 0.0f;
        for (int g = GG - 1; g >= 0; --g) {
            WV[(seq*GG + g)*8 + i] = v;
            const float* M = BM + (size_t)(seq*GG + g) * 64;
            const float a0 = v;
            GATHER8(a0, a1, a2, a3, a4, a5, a6, a7)
            const float q0 = M[(i^0)*8 + i] + a0;
            const float q1 = M[(i^1)*8 + i] + a1;
            const float q2 = M[(i^2)*8 + i] + a2;
            const float q3 = M[(i^3)*8 + i] + a3;
            const float q4 = M[(i^4)*8 + i] + a4;
            const float q5 = M[(i^5)*8 + i] + a5;
            const float q6 = M[(i^6)*8 + i] + a6;
            const float q7 = M[(i^7)*8 + i] + a7;
            float m = fmaxf(q0, q1); m = fmaxf(m, q2); m = fmaxf(m, q3);
            m = fmaxf(m, q4); m = fmaxf(m, q5); m = fmaxf(m, q6); m = fmaxf(m, q7);
            float sum = __expf(q0-m) + __expf(q1-m) + __expf(q2-m) + __expf(q3-m)
                      + __expf(q4-m) + __expf(q5-m) + __expf(q6-m) + __expf(q7-m);
            v = m + __logf(sum);
        }
    }
}

// ============ Phase C: FUSED replay + all-output bulk write ============
// ctrl packed as uint8 -> LDS 39.95 KB -> 4 blocks/CU (whole 1024-block grid resident).
__global__ __launch_bounds__(256) void fused_kernel(
    const int* __restrict__ s, const int* __restrict__ x, const float* __restrict__ mask,
    const float* __restrict__ P, const float* __restrict__ K,
    const float* __restrict__ SV, const float* __restrict__ WV,
    const float* __restrict__ loglik,
    float* __restrict__ alpha, float* __restrict__ beta,
    float* __restrict__ gamma, float* __restrict__ xi, int skipRow0)
{
    __shared__ float aLs[2 * 32 * SROW];   // log-alpha tile
    __shared__ float bLs[2 * 33 * SROW];   // log-beta tile (+ boundary slot 32 per seg)
    __shared__ float kX[340], kTt[340];    // xor-layout K and K^T
    __shared__ float lK[320];              // natural-layout logK
    __shared__ float lP0[8], lP1[8];
    __shared__ unsigned char ctrlB[2 * 33 * 8];  // packed s|x<<3|m<<4 (5 bits), slot 32 = t1

    const int tid = threadIdx.x;
    const int wv = tid >> 6, l = tid & 63;
    const int lo = l & 7, g = l >> 3;
    const int sgp = blockIdx.x >> 4;            // 64 seq-groups
    const int pairIdx = blockIdx.x & 15;        // 16 segment pairs
    const int bfirst = sgp * 8;
    const int segi = wv >> 1;                   // 0 = segA, 1 = segB
    const bool isFwd = (wv & 1) == 0;
    const int seg = pairIdx * 2 + segi;
    const int t0 = seg * LL;
    const int seq = bfirst + g;
    const int sb = seq * TT;

    // ---- stage tables + control ----
    for (int e = tid; e < 340; e += 256) {
        const int ss = e / 68, idx = e - ss * 68;
        float vX = 0.0f, vT = 0.0f;
        if (idx < 64) {
            const int row = idx >> 3, r = idx & 7;
            vX = K[ss*64 + row*8 + (row ^ r)];
            vT = K[ss*64 + (row ^ r)*8 + row];
        }
        kX[e] = vX; kTt[e] = vT;
    }
    for (int e = tid; e < 320; e += 256) lK[e] = __logf(K[e]);
    if (tid < 8) { lP0[tid] = __logf(P[tid*2]); lP1[tid] = __logf(P[tid*2+1]); }
    for (int e = tid; e < 528; e += 256) {
        const int si = e / 264, rem = e - si * 264;
        const int u = rem >> 3, gg = rem & 7;
        const int t = (pairIdx*2 + si)*LL + u;
        int cv = 0;
        if (t < TT) {
            const int a = (bfirst + gg)*TT + t;
            cv = s[a] | (x[a] << 3) | ((mask[a] != 0.0f) ? 16 : 0);
        }
        ctrlB[(si*33 + u)*8 + gg] = (unsigned char)cv;
    }
    __syncthreads();

    const float pL0 = P[lo*2+0], pL1 = P[lo*2+1];

    if (isFwd) {
        const float sv0 = SV[(seq*GG + seg)*8 + lo];
        const float mx = gmax8(sv0);
        float av = __expf(sv0 - mx);
        float c = mx;
#pragma unroll 8
        for (int u = 0; u < LL; ++u) {
            const int cw = ctrlB[(segi*33 + u)*8 + g];
            const float* kp = kX + (cw & 7)*68 + lo*8;
            const float4 k0 = *(const float4*)kp;
            const float4 k1 = *(const float4*)(kp + 4);
            const float a0 = av;
            GATHER8(a0, a1, a2, a3, a4, a5, a6, a7)
            FMASUM(acc, k0, k1, a0,a1,a2,a3,a4,a5,a6,a7)
            const float nv = acc * ((cw & 8) ? pL1 : pL0);
            av = (cw & 16) ? nv : av;
            if ((u & 7) == 7) {
                const float ms = gmax8(av);
                av *= __builtin_amdgcn_rcpf(ms);
                c += __logf(ms);
            }
            aLs[(segi*32 + u)*SROW + g*8 + lo] = __logf(av) + c;
        }
    } else {
        const float w0 = WV[(seq*GG + seg)*8 + lo];
        const float llv = loglik[seq];
        const float mx = gmax8(w0);
        float bv = __expf(w0 - mx);
        float c = mx - llv;
        bLs[(segi*33 + 32)*SROW + g*8 + lo] = w0 - llv;   // normalized beta[t1]
        const int t1 = t0 + LL;
        int m1 = ctrlB[(segi*33 + 32)*8 + g] & 16;
        int sxc = 0;
        {   // per-group bounded search for first masked index >= t1 (R12-verified)
            int tt = t1;
            int found = (t1 >= TT) ? 1 : 0;
            while (!__all(found)) {
                if (!found && tt < TT) {
                    if (mask[sb + tt] != 0.0f) { sxc = s[sb+tt] | (x[sb+tt] << 3); found = 1; }
                }
                if (tt >= TT - 1) found = 1;
                ++tt;
            }
        }
#pragma unroll 8
        for (int u = LL - 1; u >= 0; --u) {
            const int cw = ctrlB[(segi*33 + u)*8 + g];
            const float* kp = kTt + (sxc & 7)*68 + lo*8;
            const float4 k0 = *(const float4*)kp;
            const float4 k1 = *(const float4*)(kp + 4);
            const float u0 = bv * ((sxc & 8) ? pL1 : pL0);
            GATHER8(u0, u1, u2, u3, u4, u5, u6, u7)
            FMASUM(acc, k0, k1, u0,u1,u2,u3,u4,u5,u6,u7)
            bv = m1 ? acc : bv;
            if ((u & 7) == 0) {
                const float ms = gmax8(bv);
                bv *= __builtin_amdgcn_rcpf(ms);
                c += __logf(ms);
            }
            bLs[(segi*33 + u)*SROW + g*8 + lo] = __logf(bv) + c;
            sxc = (cw & 16) ? (cw & 15) : sxc;
            m1 = cw & 16;
        }
    }
    __syncthreads();

    // ---- bulk coalesced write phase ----
    const int t0base = pairIdx * 64;
    // alpha / beta / gamma: 4096 floats each = 1024 float4 -> 4 iters
    for (int it = 0; it < 4; ++it) {
        const int f4 = it*256 + tid;            // [0,1024)
        const int sq = f4 >> 7;                 // 128 float4 per seq
        const int rem = f4 & 127;
        const int tl = rem >> 1, z4 = (rem & 1) * 4;
        const int si = tl >> 5, u = tl & 31;
        const size_t gbase = ((size_t)(bfirst+sq)*TT + t0base + tl)*8 + z4;
        const float4 av4 = *(const float4*)&aLs[(si*32+u)*SROW + sq*8 + z4];
        const float4 bv4 = *(const float4*)&bLs[(si*33+u)*SROW + sq*8 + z4];
        __builtin_nontemporal_store(__builtin_bit_cast(fvec4, av4), (fvec4*)&alpha[gbase]);
        __builtin_nontemporal_store(__builtin_bit_cast(fvec4, bv4), (fvec4*)&beta[gbase]);
        float4 gv;
        if (ctrlB[(si*33+u)*8 + sq] & 16) {
            gv.x = av4.x + bv4.x; gv.y = av4.y + bv4.y;
            gv.z = av4.z + bv4.z; gv.w = av4.w + bv4.w;
        } else { gv.x = NINF; gv.y = NINF; gv.z = NINF; gv.w = NINF; }
        __builtin_nontemporal_store(__builtin_bit_cast(fvec4, gv), (fvec4*)&gamma[gbase]);
    }
    // xi: 512 rows x 16 float4 = 8192 float4 -> 32 iters
    for (int it = 0; it < 32; ++it) {
        const int f4 = it*256 + tid;
        const int r = f4 >> 4, ll2 = f4 & 15;
        const int sq = r >> 6, tl = r & 63;
        const int t = t0base + tl;
        if (t >= TT - 1) continue;
        const int rowLin = (bfirst + sq)*(TT - 1) + t;
        if (rowLin >= skipRow0) continue;          // xi-tail scratch protection
        const int si = tl >> 5, u = tl & 31;
        const int cw  = ctrlB[(si*33 + u)*8 + sq];
        const int cw1 = ctrlB[(si*33 + u + 1)*8 + sq];
        float4 o;
        if (cw1 & 16) {
            const int i = ll2 >> 1, bj = (ll2 & 1)*4;
            const float aHi = aLs[(si*32 + u)*SROW + sq*8 + i];
            const float4 bN = *(const float4*)&bLs[(si*33 + u + 1)*SROW + sq*8 + bj];
            const float4 kv = *(const float4*)&lK[(cw & 7)*64 + ll2*4];
            const float4 p0 = *(const float4*)&lP0[bj];
            const float4 p1 = *(const float4*)&lP1[bj];
            const int xv = (cw1 >> 3) & 1;
            o.x = kv.x + aHi + bN.x + (xv ? p1.x : p0.x);
            o.y = kv.y + aHi + bN.y + (xv ? p1.y : p0.y);
            o.z = kv.z + aHi + bN.z + (xv ? p1.z : p0.z);
            o.w = kv.w + aHi + bN.w + (xv ? p1.w : p0.w);
        } else { o.x = NINF; o.y = NINF; o.z = NINF; o.w = NINF; }
        __builtin_nontemporal_store(__builtin_bit_cast(fvec4, o),
                                    (fvec4*)&xi[(size_t)rowLin*64 + ll2*4]);
    }
}

// ============ xi tail fixup (only when scratch lives in xi's tail) ============
__global__ __launch_bounds__(256) void xi_fixup_kernel(
    const int* __restrict__ s, const int* __restrict__ x, const float* __restrict__ mask,
    const float* __restrict__ P, const float* __restrict__ K,
    const float* __restrict__ alpha, const float* __restrict__ beta,
    float* __restrict__ xi)
{
    __shared__ float lK[320], lP[16];
    const int tid = threadIdx.x;
    for (int e = tid; e < 320; e += 256) lK[e] = __logf(K[e]);
    if (tid < 16) lP[tid] = __logf(P[tid]);
    __syncthreads();

    const int wv = tid >> 6, l = tid & 63;
    const int row = SCRATCH_ROW0 + blockIdx.x * 4 + wv;
    if (row >= NXROWS) return;
    const int b = row / (TT - 1);
    const int t = row - b * (TT - 1);
    const long bt = (long)b * TT + t;
    float xo = NINF;
    if (mask[bt + 1] != 0.0f) {
        const int sv = s[bt];
        const int xv = x[bt + 1];
        const float aHi = alpha[bt*8 + (l >> 3)];
        const float bN  = beta[(bt + 1)*8 + (l & 7)];
        xo = lK[sv*64 + l] + aHi + bN + lP[(l & 7)*2 + xv];
    }
    xi[(size_t)row*64 + l] = xo;
}

extern "C" void kernel_launch(void* const* d_in, const int* in_sizes, int n_in,
                              void* d_out, int out_size, void* d_ws, size_t ws_size,
                              hipStream_t stream) {
    const int*   s    = (const int*)d_in[0];
    const int*   x    = (const int*)d_in[1];
    const float* mask = (const float*)d_in[2];
    const float* pi   = (const float*)d_in[3];
    const float* P    = (const float*)d_in[4];
    const float* K    = (const float*)d_in[5];

    float* out    = (float*)d_out;
    float* gamma  = out;                                  // (B,T,Z)
    float* xi     = gamma + (size_t)BB * TT * 8;          // (B,T-1,Z,Z)
    float* alpha  = xi + (size_t)BB * (TT - 1) * 64;      // (B,T,Z)
    float* beta   = alpha + (size_t)BB * TT * 8;          // (B,T,Z)
    float* loglik = beta + (size_t)BB * TT * 8;           // (B,)

    const size_t scratchFloats = (size_t)2*BB*GG*64 + (size_t)2*BB*GG*8;  // FM,BM,SV,WV
    const bool useWs = ws_size >= scratchFloats * sizeof(float);
    float* FMs = useWs ? (float*)d_ws : xi + (size_t)31000000;
    float* BMs = FMs + (size_t)BB * GG * 64;
    float* SVs = BMs + (size_t)BB * GG * 64;
    float* WVs = SVs + (size_t)BB * GG * 8;
    const int skipRow0 = useWs ? 0x7FFFFFFF : SCRATCH_ROW0;

    segmat_kernel<<<8192, 256, 0, stream>>>(s, x, mask, P, K, FMs, BMs);
    compose_kernel<<<32, 256, 0, stream>>>(pi, FMs, BMs, SVs, WVs, loglik);
    fused_kernel<<<1024, 256, 0, stream>>>(s, x, mask, P, K, SVs, WVs, loglik,
                                           alpha, beta, gamma, xi, skipRow0);
    if (!useWs) {
        const int tailRows = NXROWS - SCRATCH_ROW0;
        xi_fixup_kernel<<<(tailRows + 3) / 4, 256, 0, stream>>>(
            s, x, mask, P, K, alpha, beta, xi);
    }
}

// Round 16
// 105.083 us; speedup vs baseline: 1.5041x; 1.0247x over previous
//
#include <hip/hip_runtime.h>

#define BB 512
#define TT 1024
#define GG 32
#define LL 32
#define NINF -10000000000.0f
#define SROW 68                 // LDS row stride (floats): mult of 4 for b128 alignment
#define NXROWS (BB * (TT - 1))  // 523776 xi rows
#define SCRATCH_ROW0 484375     // xi row where xi-tail scratch begins (31,000,000/64)

// DPP ctrls: quad_perm xor1=0xB1, xor2=0x4E; row_half_mirror(^7)=0x141
template<int CTRL>
__device__ __forceinline__ float dppf(float x) {
    return __builtin_bit_cast(float, __builtin_amdgcn_update_dpp(
        0, __builtin_bit_cast(int, x), CTRL, 0xF, 0xF, true));
}
__device__ __forceinline__ float gsum8(float x) {
    x += dppf<0xB1>(x); x += dppf<0x4E>(x); x += dppf<0x141>(x); return x;
}
__device__ __forceinline__ float gmax8(float x) {
    x = fmaxf(x, dppf<0xB1>(x)); x = fmaxf(x, dppf<0x4E>(x)); x = fmaxf(x, dppf<0x141>(x)); return x;
}

#define GATHER8(A0, A1, A2, A3, A4, A5, A6, A7)      \
    const float A1 = dppf<0xB1>(A0);                 \
    const float A2 = dppf<0x4E>(A0);                 \
    const float A7 = dppf<0x141>(A0);                \
    const float A3 = dppf<0x4E>(A1);                 \
    const float A6 = dppf<0xB1>(A7);                 \
    const float A5 = dppf<0x4E>(A7);                 \
    const float A4 = dppf<0x4E>(A6);

#define FMASUM(ACC, K0, K1, A0,A1,A2,A3,A4,A5,A6,A7) \
    float ACC;                                       \
    {   float accA = K0.x * A0;                      \
        accA = fmaf(K0.y, A1, accA);                 \
        accA = fmaf(K0.z, A2, accA);                 \
        accA = fmaf(K0.w, A3, accA);                 \
        float accB = K1.x * A4;                      \
        accB = fmaf(K1.y, A5, accB);                 \
        accB = fmaf(K1.z, A6, accB);                 \
        ACC = accA + accB; }

// ============ Phase A: per-segment 8x8 transfer matrices (R15-verified) ============
__global__ __launch_bounds__(256) void segmat_kernel(
    const int* __restrict__ s, const int* __restrict__ x, const float* __restrict__ mask,
    const float* __restrict__ P, const float* __restrict__ K,
    float* __restrict__ FM, float* __restrict__ BM)
{
    __shared__ float kTab[5 * 68];
    __shared__ int   ctrlA[4][LL];
    const int tid = threadIdx.x;
    const int wv = tid >> 6, l = tid & 63;
    const int lo = l & 7, hi = l >> 3;
    const bool isF = blockIdx.x < 4096;
    const int task = (isF ? blockIdx.x : blockIdx.x - 4096) * 4 + wv;
    const int seq = task >> 5, seg = task & 31;
    const int sb = seq * TT;
    const int t0 = seg * LL;

    for (int e = tid; e < 340; e += 256) {
        const int ss = e / 68, idx = e - ss * 68;
        float v = 0.0f;
        if (idx < 64) {
            const int row = idx >> 3, r = idx & 7;
            v = isF ? K[ss*64 + row*8 + (row ^ r)]
                    : K[ss*64 + (row ^ r)*8 + row];
        }
        kTab[e] = v;
    }
    if (l < LL) {
        const int tt = t0 + l;
        ctrlA[wv][l] = s[sb+tt] | (x[sb+tt] << 3) | ((mask[sb+tt] != 0.0f) ? 16 : 0);
    }
    __syncthreads();

    const float pL0 = P[lo*2+0], pL1 = P[lo*2+1];
    const float* kbase = kTab + lo*8;
    float av = (lo == hi) ? 1.0f : 0.0f;
    float c = 0.0f;

    if (isF) {
#pragma unroll 8
        for (int u = 0; u < LL; ++u) {
            const int cw = __builtin_amdgcn_readfirstlane(ctrlA[wv][u]);
            if (cw & 16) {
                const float* kp = kbase + (cw & 7) * 68;
                const float4 k0 = *(const float4*)kp;
                const float4 k1 = *(const float4*)(kp + 4);
                const float a0 = av;
                GATHER8(a0, a1, a2, a3, a4, a5, a6, a7)
                FMASUM(acc, k0, k1, a0,a1,a2,a3,a4,a5,a6,a7)
                av = acc * ((cw & 8) ? pL1 : pL0);
            }
            if ((u & 7) == 7) {
                const float ms = gmax8(av);
                av *= __builtin_amdgcn_rcpf(ms);
                c += __logf(ms);
            }
        }
        FM[task*64 + l] = __logf(av) + c;
    } else {
        const int t1 = t0 + LL;
        int sxc = 0;
        for (int tt = t1; tt < TT; ++tt) {
            if (mask[sb + tt] != 0.0f) { sxc = s[sb+tt] | (x[sb+tt] << 3); break; }
        }
        int m1 = (t1 < TT && mask[sb + t1] != 0.0f) ? 16 : 0;
        sxc = __builtin_amdgcn_readfirstlane(sxc);
        m1  = __builtin_amdgcn_readfirstlane(m1);
#pragma unroll 8
        for (int u = LL - 1; u >= 0; --u) {
            const int cw = __builtin_amdgcn_readfirstlane(ctrlA[wv][u]);
            if (m1) {
                const float* kp = kbase + (sxc & 7) * 68;
                const float4 k0 = *(const float4*)kp;
                const float4 k1 = *(const float4*)(kp + 4);
                const float u0 = av * ((sxc & 8) ? pL1 : pL0);
                GATHER8(u0, u1, u2, u3, u4, u5, u6, u7)
                FMASUM(acc, k0, k1, u0,u1,u2,u3,u4,u5,u6,u7)
                av = acc;
            }
            sxc = (cw & 16) ? (cw & 15) : sxc;
            m1 = cw & 16;
            if ((u & 7) == 0) {
                const float ms = gmax8(av);
                av *= __builtin_amdgcn_rcpf(ms);
                c += __logf(ms);
            }
        }
        BM[task*64 + l] = __logf(av) + c;
    }
}

// ============ Phase B: compose (R12-verified) ============
__global__ __launch_bounds__(256) void compose_kernel(
    const float* __restrict__ pi, const float* __restrict__ FM, const float* __restrict__ BM,
    float* __restrict__ SV, float* __restrict__ WV, float* __restrict__ loglik)
{
    const int tid = threadIdx.x;
    const int grp = blockIdx.x * 32 + (tid >> 3);
    const int i = tid & 7;
    if (grp < BB) {
        const int seq = grp;
        float v = __logf(pi[i]);
        for (int g = 0; g < GG; ++g) {
            SV[(seq*GG + g)*8 + i] = v;
            const float* M = FM + (size_t)(seq*GG + g) * 64;
            const float a0 = v;
            GATHER8(a0, a1, a2, a3, a4, a5, a6, a7)
            const float q0 = M[(i^0)*8 + i] + a0;
            const float q1 = M[(i^1)*8 + i] + a1;
            const float q2 = M[(i^2)*8 + i] + a2;
            const float q3 = M[(i^3)*8 + i] + a3;
            const float q4 = M[(i^4)*8 + i] + a4;
            const float q5 = M[(i^5)*8 + i] + a5;
            const float q6 = M[(i^6)*8 + i] + a6;
            const float q7 = M[(i^7)*8 + i] + a7;
            float m = fmaxf(q0, q1); m = fmaxf(m, q2); m = fmaxf(m, q3);
            m = fmaxf(m, q4); m = fmaxf(m, q5); m = fmaxf(m, q6); m = fmaxf(m, q7);
            float sum = __expf(q0-m) + __expf(q1-m) + __expf(q2-m) + __expf(q3-m)
                      + __expf(q4-m) + __expf(q5-m) + __expf(q6-m) + __expf(q7-m);
            v = m + __logf(sum);
        }
        const float gm = gmax8(v);
        const float ge = gsum8(__expf(v - gm));
        if (i == 0) loglik[seq] = gm + __logf(ge);
    } else {
        const int seq = grp - BB;
        float v = 0.0f;
        for (int g = GG - 1; g >= 0; --g) {
            WV[(seq*GG + g)*8 + i] = v;
            const float* M = BM + (size_t)(seq*GG + g) * 64;
            const float a0 = v;
            GATHER8(a0, a1, a2, a3, a4, a5, a6, a7)
            const float q0 = M[(i^0)*8 + i] + a0;
            const float q1 = M[(i^1)*8 + i] + a1;
            const float q2 = M[(i^2)*8 + i] + a2;
            const float q3 = M[(i^3)*8 + i] + a3;
            const float q4 = M[(i^4)*8 + i] + a4;
            const float q5 = M[(i^5)*8 + i] + a5;
            const float q6 = M[(i^6)*8 + i] + a6;
            const float q7 = M[(i^7)*8 + i] + a7;
            float m = fmaxf(q0, q1); m = fmaxf(m, q2); m = fmaxf(m, q3);
            m = fmaxf(m, q4); m = fmaxf(m, q5); m = fmaxf(m, q6); m = fmaxf(m, q7);
            float sum = __expf(q0-m) + __expf(q1-m) + __expf(q2-m) + __expf(q3-m)
                      + __expf(q4-m) + __expf(q5-m) + __expf(q6-m) + __expf(q7-m);
            v = m + __logf(sum);
        }
    }
}

// ============ Phase C: FUSED replay + all-output bulk write ============
// Identical to R15 except: all output stores are REGULAR (L2-absorbed), not nt.
__global__ __launch_bounds__(256) void fused_kernel(
    const int* __restrict__ s, const int* __restrict__ x, const float* __restrict__ mask,
    const float* __restrict__ P, const float* __restrict__ K,
    const float* __restrict__ SV, const float* __restrict__ WV,
    const float* __restrict__ loglik,
    float* __restrict__ alpha, float* __restrict__ beta,
    float* __restrict__ gamma, float* __restrict__ xi, int skipRow0)
{
    __shared__ float aLs[2 * 32 * SROW];   // log-alpha tile
    __shared__ float bLs[2 * 33 * SROW];   // log-beta tile (+ boundary slot 32 per seg)
    __shared__ float kX[340], kTt[340];    // xor-layout K and K^T
    __shared__ float lK[320];              // natural-layout logK
    __shared__ float lP0[8], lP1[8];
    __shared__ unsigned char ctrlB[2 * 33 * 8];  // packed s|x<<3|m<<4 (5 bits), slot 32 = t1

    const int tid = threadIdx.x;
    const int wv = tid >> 6, l = tid & 63;
    const int lo = l & 7, g = l >> 3;
    const int sgp = blockIdx.x >> 4;            // 64 seq-groups
    const int pairIdx = blockIdx.x & 15;        // 16 segment pairs
    const int bfirst = sgp * 8;
    const int segi = wv >> 1;                   // 0 = segA, 1 = segB
    const bool isFwd = (wv & 1) == 0;
    const int seg = pairIdx * 2 + segi;
    const int t0 = seg * LL;
    const int seq = bfirst + g;
    const int sb = seq * TT;

    // ---- stage tables + control ----
    for (int e = tid; e < 340; e += 256) {
        const int ss = e / 68, idx = e - ss * 68;
        float vX = 0.0f, vT = 0.0f;
        if (idx < 64) {
            const int row = idx >> 3, r = idx & 7;
            vX = K[ss*64 + row*8 + (row ^ r)];
            vT = K[ss*64 + (row ^ r)*8 + row];
        }
        kX[e] = vX; kTt[e] = vT;
    }
    for (int e = tid; e < 320; e += 256) lK[e] = __logf(K[e]);
    if (tid < 8) { lP0[tid] = __logf(P[tid*2]); lP1[tid] = __logf(P[tid*2+1]); }
    for (int e = tid; e < 528; e += 256) {
        const int si = e / 264, rem = e - si * 264;
        const int u = rem >> 3, gg = rem & 7;
        const int t = (pairIdx*2 + si)*LL + u;
        int cv = 0;
        if (t < TT) {
            const int a = (bfirst + gg)*TT + t;
            cv = s[a] | (x[a] << 3) | ((mask[a] != 0.0f) ? 16 : 0);
        }
        ctrlB[(si*33 + u)*8 + gg] = (unsigned char)cv;
    }
    __syncthreads();

    const float pL0 = P[lo*2+0], pL1 = P[lo*2+1];

    if (isFwd) {
        const float sv0 = SV[(seq*GG + seg)*8 + lo];
        const float mx = gmax8(sv0);
        float av = __expf(sv0 - mx);
        float c = mx;
#pragma unroll 8
        for (int u = 0; u < LL; ++u) {
            const int cw = ctrlB[(segi*33 + u)*8 + g];
            const float* kp = kX + (cw & 7)*68 + lo*8;
            const float4 k0 = *(const float4*)kp;
            const float4 k1 = *(const float4*)(kp + 4);
            const float a0 = av;
            GATHER8(a0, a1, a2, a3, a4, a5, a6, a7)
            FMASUM(acc, k0, k1, a0,a1,a2,a3,a4,a5,a6,a7)
            const float nv = acc * ((cw & 8) ? pL1 : pL0);
            av = (cw & 16) ? nv : av;
            if ((u & 7) == 7) {
                const float ms = gmax8(av);
                av *= __builtin_amdgcn_rcpf(ms);
                c += __logf(ms);
            }
            aLs[(segi*32 + u)*SROW + g*8 + lo] = __logf(av) + c;
        }
    } else {
        const float w0 = WV[(seq*GG + seg)*8 + lo];
        const float llv = loglik[seq];
        const float mx = gmax8(w0);
        float bv = __expf(w0 - mx);
        float c = mx - llv;
        bLs[(segi*33 + 32)*SROW + g*8 + lo] = w0 - llv;   // normalized beta[t1]
        const int t1 = t0 + LL;
        int m1 = ctrlB[(segi*33 + 32)*8 + g] & 16;
        int sxc = 0;
        {   // per-group bounded search for first masked index >= t1 (R12-verified)
            int tt = t1;
            int found = (t1 >= TT) ? 1 : 0;
            while (!__all(found)) {
                if (!found && tt < TT) {
                    if (mask[sb + tt] != 0.0f) { sxc = s[sb+tt] | (x[sb+tt] << 3); found = 1; }
                }
                if (tt >= TT - 1) found = 1;
                ++tt;
            }
        }
#pragma unroll 8
        for (int u = LL - 1; u >= 0; --u) {
            const int cw = ctrlB[(segi*33 + u)*8 + g];
            const float* kp = kTt + (sxc & 7)*68 + lo*8;
            const float4 k0 = *(const float4*)kp;
            const float4 k1 = *(const float4*)(kp + 4);
            const float u0 = bv * ((sxc & 8) ? pL1 : pL0);
            GATHER8(u0, u1, u2, u3, u4, u5, u6, u7)
            FMASUM(acc, k0, k1, u0,u1,u2,u3,u4,u5,u6,u7)
            bv = m1 ? acc : bv;
            if ((u & 7) == 0) {
                const float ms = gmax8(bv);
                bv *= __builtin_amdgcn_rcpf(ms);
                c += __logf(ms);
            }
            bLs[(segi*33 + u)*SROW + g*8 + lo] = __logf(bv) + c;
            sxc = (cw & 16) ? (cw & 15) : sxc;
            m1 = cw & 16;
        }
    }
    __syncthreads();

    // ---- bulk coalesced write phase (regular stores) ----
    const int t0base = pairIdx * 64;
    // alpha / beta / gamma: 4096 floats each = 1024 float4 -> 4 iters
    for (int it = 0; it < 4; ++it) {
        const int f4 = it*256 + tid;            // [0,1024)
        const int sq = f4 >> 7;                 // 128 float4 per seq
        const int rem = f4 & 127;
        const int tl = rem >> 1, z4 = (rem & 1) * 4;
        const int si = tl >> 5, u = tl & 31;
        const size_t gbase = ((size_t)(bfirst+sq)*TT + t0base + tl)*8 + z4;
        const float4 av4 = *(const float4*)&aLs[(si*32+u)*SROW + sq*8 + z4];
        const float4 bv4 = *(const float4*)&bLs[(si*33+u)*SROW + sq*8 + z4];
        *(float4*)&alpha[gbase] = av4;
        *(float4*)&beta[gbase]  = bv4;
        float4 gv;
        if (ctrlB[(si*33+u)*8 + sq] & 16) {
            gv.x = av4.x + bv4.x; gv.y = av4.y + bv4.y;
            gv.z = av4.z + bv4.z; gv.w = av4.w + bv4.w;
        } else { gv.x = NINF; gv.y = NINF; gv.z = NINF; gv.w = NINF; }
        *(float4*)&gamma[gbase] = gv;
    }
    // xi: 512 rows x 16 float4 = 8192 float4 -> 32 iters
    for (int it = 0; it < 32; ++it) {
        const int f4 = it*256 + tid;
        const int r = f4 >> 4, ll2 = f4 & 15;
        const int sq = r >> 6, tl = r & 63;
        const int t = t0base + tl;
        if (t >= TT - 1) continue;
        const int rowLin = (bfirst + sq)*(TT - 1) + t;
        if (rowLin >= skipRow0) continue;          // xi-tail scratch protection
        const int si = tl >> 5, u = tl & 31;
        const int cw  = ctrlB[(si*33 + u)*8 + sq];
        const int cw1 = ctrlB[(si*33 + u + 1)*8 + sq];
        float4 o;
        if (cw1 & 16) {
            const int i = ll2 >> 1, bj = (ll2 & 1)*4;
            const float aHi = aLs[(si*32 + u)*SROW + sq*8 + i];
            const float4 bN = *(const float4*)&bLs[(si*33 + u + 1)*SROW + sq*8 + bj];
            const float4 kv = *(const float4*)&lK[(cw & 7)*64 + ll2*4];
            const float4 p0 = *(const float4*)&lP0[bj];
            const float4 p1 = *(const float4*)&lP1[bj];
            const int xv = (cw1 >> 3) & 1;
            o.x = kv.x + aHi + bN.x + (xv ? p1.x : p0.x);
            o.y = kv.y + aHi + bN.y + (xv ? p1.y : p0.y);
            o.z = kv.z + aHi + bN.z + (xv ? p1.z : p0.z);
            o.w = kv.w + aHi + bN.w + (xv ? p1.w : p0.w);
        } else { o.x = NINF; o.y = NINF; o.z = NINF; o.w = NINF; }
        *(float4*)&xi[(size_t)rowLin*64 + ll2*4] = o;
    }
}

// ============ xi tail fixup (only when scratch lives in xi's tail) ============
__global__ __launch_bounds__(256) void xi_fixup_kernel(
    const int* __restrict__ s, const int* __restrict__ x, const float* __restrict__ mask,
    const float* __restrict__ P, const float* __restrict__ K,
    const float* __restrict__ alpha, const float* __restrict__ beta,
    float* __restrict__ xi)
{
    __shared__ float lK[320], lP[16];
    const int tid = threadIdx.x;
    for (int e = tid; e < 320; e += 256) lK[e] = __logf(K[e]);
    if (tid < 16) lP[tid] = __logf(P[tid]);
    __syncthreads();

    const int wv = tid >> 6, l = tid & 63;
    const int row = SCRATCH_ROW0 + blockIdx.x * 4 + wv;
    if (row >= NXROWS) return;
    const int b = row / (TT - 1);
    const int t = row - b * (TT - 1);
    const long bt = (long)b * TT + t;
    float xo = NINF;
    if (mask[bt + 1] != 0.0f) {
        const int sv = s[bt];
        const int xv = x[bt + 1];
        const float aHi = alpha[bt*8 + (l >> 3)];
        const float bN  = beta[(bt + 1)*8 + (l & 7)];
        xo = lK[sv*64 + l] + aHi + bN + lP[(l & 7)*2 + xv];
    }
    xi[(size_t)row*64 + l] = xo;
}

extern "C" void kernel_launch(void* const* d_in, const int* in_sizes, int n_in,
                              void* d_out, int out_size, void* d_ws, size_t ws_size,
                              hipStream_t stream) {
    const int*   s    = (const int*)d_in[0];
    const int*   x    = (const int*)d_in[1];
    const float* mask = (const float*)d_in[2];
    const float* pi   = (const float*)d_in[3];
    const float* P    = (const float*)d_in[4];
    const float* K    = (const float*)d_in[5];

    float* out    = (float*)d_out;
    float* gamma  = out;                                  // (B,T,Z)
    float* xi     = gamma + (size_t)BB * TT * 8;          // (B,T-1,Z,Z)
    float* alpha  = xi + (size_t)BB * (TT - 1) * 64;      // (B,T,Z)
    float* beta   = alpha + (size_t)BB * TT * 8;          // (B,T,Z)
    float* loglik = beta + (size_t)BB * TT * 8;           // (B,)

    const size_t scratchFloats = (size_t)2*BB*GG*64 + (size_t)2*BB*GG*8;  // FM,BM,SV,WV
    const bool useWs = ws_size >= scratchFloats * sizeof(float);
    float* FMs = useWs ? (float*)d_ws : xi + (size_t)31000000;
    float* BMs = FMs + (size_t)BB * GG * 64;
    float* SVs = BMs + (size_t)BB * GG * 64;
    float* WVs = SVs + (size_t)BB * GG * 8;
    const int skipRow0 = useWs ? 0x7FFFFFFF : SCRATCH_ROW0;

    segmat_kernel<<<8192, 256, 0, stream>>>(s, x, mask, P, K, FMs, BMs);
    compose_kernel<<<32, 256, 0, stream>>>(pi, FMs, BMs, SVs, WVs, loglik);
    fused_kernel<<<1024, 256, 0, stream>>>(s, x, mask, P, K, SVs, WVs, loglik,
                                           alpha, beta, gamma, xi, skipRow0);
    if (!useWs) {
        const int tailRows = NXROWS - SCRATCH_ROW0;
        xi_fixup_kernel<<<(tailRows + 3) / 4, 256, 0, stream>>>(
            s, x, mask, P, K, alpha, beta, xi);
    }
}